// Round 1
// baseline (314.407 us; speedup 1.0000x reference)
//
#include <hip/hip_runtime.h>
#include <math.h>

#define N_NODES 20000
#define E_RAW   320000
#define E_TOT   (E_RAW + N_NODES)
#define IN_CH   256
#define HEADS   8
#define HID     32
#define HH      (HEADS*HID)   // 256
#define OUT_CH  40
#define NEG     0.2f

// ---------------- CSR build ----------------

__global__ void zero_kernel(int* p, int n) {
    int i = blockIdx.x * 256 + threadIdx.x;
    if (i < n) p[i] = 0;
}

__global__ void hist_kernel(const int* __restrict__ ei, int* __restrict__ deg) {
    int e = blockIdx.x * 256 + threadIdx.x;
    if (e >= E_TOT) return;
    int d = (e < E_RAW) ? ei[E_RAW + e] : (e - E_RAW);
    atomicAdd(&deg[d], 1);
}

__global__ __launch_bounds__(1024) void scan_kernel(const int* __restrict__ deg,
                                                    int* __restrict__ offs) {
    __shared__ int part[1024];
    int t = threadIdx.x;
    const int chunk = (N_NODES + 1023) / 1024;  // 20
    int begin = t * chunk;
    int end = begin + chunk; if (end > N_NODES) end = N_NODES;
    if (begin > N_NODES) begin = N_NODES;
    int s = 0;
    for (int i = begin; i < end; i++) s += deg[i];
    part[t] = s;
    __syncthreads();
    for (int off = 1; off < 1024; off <<= 1) {
        int v = (t >= off) ? part[t - off] : 0;
        __syncthreads();
        part[t] += v;
        __syncthreads();
    }
    int run = (t == 0) ? 0 : part[t - 1];
    for (int i = begin; i < end; i++) { offs[i] = run; run += deg[i]; }
    if (t == 1023) offs[N_NODES] = part[1023];
}

__global__ void scatter_kernel(const int* __restrict__ ei, const int* __restrict__ offs,
                               int* __restrict__ cursor, int* __restrict__ csr) {
    int e = blockIdx.x * 256 + threadIdx.x;
    if (e >= E_TOT) return;
    int s, d;
    if (e < E_RAW) { s = ei[e]; d = ei[E_RAW + e]; }
    else           { s = e - E_RAW; d = s; }
    int pos = atomicAdd(&cursor[d], 1);
    csr[offs[d] + pos] = s;
}

// ---------------- Layer 1 GEMM + alpha ----------------

#define TM1 16
__global__ __launch_bounds__(256) void gemm1(const float* __restrict__ x,
                                             const float* __restrict__ W1,
                                             const float* __restrict__ a1s,
                                             const float* __restrict__ a1d,
                                             float* __restrict__ h1,
                                             float* __restrict__ as1,
                                             float* __restrict__ ad1) {
    __shared__ float xs[TM1][IN_CH];   // 16 KiB
    int c = threadIdx.x;               // output column 0..255
    int n0 = blockIdx.x * TM1;
    #pragma unroll
    for (int m = 0; m < TM1; m++)
        xs[m][c] = x[(size_t)(n0 + m) * IN_CH + c];
    __syncthreads();

    float acc[TM1];
    #pragma unroll
    for (int m = 0; m < TM1; m++) acc[m] = 0.f;

    for (int k = 0; k < IN_CH; k += 4) {
        float w0 = W1[(size_t)(k + 0) * HH + c];
        float w1 = W1[(size_t)(k + 1) * HH + c];
        float w2 = W1[(size_t)(k + 2) * HH + c];
        float w3 = W1[(size_t)(k + 3) * HH + c];
        #pragma unroll
        for (int m = 0; m < TM1; m++) {
            float4 xv = *reinterpret_cast<const float4*>(&xs[m][k]);
            acc[m] = fmaf(xv.x, w0, acc[m]);
            acc[m] = fmaf(xv.y, w1, acc[m]);
            acc[m] = fmaf(xv.z, w2, acc[m]);
            acc[m] = fmaf(xv.w, w3, acc[m]);
        }
    }

    float asc = a1s[c], adc = a1d[c];
    #pragma unroll
    for (int m = 0; m < TM1; m++) {
        int n = n0 + m;
        h1[(size_t)n * HH + c] = acc[m];
        float vs = acc[m] * asc;
        float vd = acc[m] * adc;
        #pragma unroll
        for (int off = 16; off >= 1; off >>= 1) {
            vs += __shfl_xor(vs, off);
            vd += __shfl_xor(vd, off);
        }
        if ((c & 31) == 0) {
            int h = c >> 5;
            as1[n * HEADS + h] = vs;
            ad1[n * HEADS + h] = vd;
        }
    }
}

// ---------------- Layer 1 attention + aggregate + bias + ELU ----------------

__global__ __launch_bounds__(256) void aggr1(const float* __restrict__ h1,
                                             const float* __restrict__ as1,
                                             const float* __restrict__ ad1,
                                             const float* __restrict__ b1,
                                             const int* __restrict__ offs,
                                             const int* __restrict__ csr,
                                             float* __restrict__ h2) {
    int d = blockIdx.x;
    int t = threadIdx.x;
    int start = offs[d];
    int deg = offs[d + 1] - start;
    int j = t & 31;      // edge slot
    int h = t >> 5;      // head (also the head of channel c=t)

    float adv = ad1[d * HEADS + h];

    // phase 1: online softmax stats (max & sum) per head
    float m_l = -1e30f, s_l = 0.f;
    for (int base = 0; base < deg; base += 32) {
        int jj = base + j;
        if (jj < deg) {
            int s = csr[start + jj];
            float v = as1[s * HEADS + h] + adv;
            v = (v > 0.f) ? v : NEG * v;
            float nm = fmaxf(m_l, v);
            s_l = s_l * __expf(m_l - nm) + __expf(v - nm);
            m_l = nm;
        }
    }
    #pragma unroll
    for (int off = 16; off >= 1; off >>= 1) {
        float m_o = __shfl_xor(m_l, off);
        float s_o = __shfl_xor(s_l, off);
        float nm = fmaxf(m_l, m_o);
        s_l = s_l * __expf(m_l - nm) + s_o * __expf(m_o - nm);
        m_l = nm;
    }

    __shared__ float mh[HEADS], sh[HEADS];
    __shared__ float wbuf[32][HEADS + 1];
    __shared__ int   sbuf[32];
    if (j == 0) { mh[h] = m_l; sh[h] = s_l; }
    __syncthreads();

    float mhv = mh[h];
    float inv = 1.0f / (sh[h] + 1e-16f);

    float acc = 0.f;
    int c = t;
    for (int base = 0; base < deg; base += 32) {
        int jj = base + j;
        if (jj < deg) {
            int s = csr[start + jj];
            float v = as1[s * HEADS + h] + adv;
            v = (v > 0.f) ? v : NEG * v;
            wbuf[j][h] = __expf(v - mhv) * inv;
            if (h == 0) sbuf[j] = s;
        }
        __syncthreads();
        int lim = deg - base; if (lim > 32) lim = 32;
        for (int j2 = 0; j2 < lim; j2++) {
            int s = sbuf[j2];
            acc = fmaf(h1[(size_t)s * HH + c], wbuf[j2][h], acc);
        }
        __syncthreads();
    }

    float r = acc + b1[c];
    r = (r > 0.f) ? r : (__expf(r) - 1.f);   // ELU
    h2[(size_t)d * HH + c] = r;
}

// ---------------- Layer 2 GEMM + alpha ----------------

#define TM2 8
__global__ __launch_bounds__(320) void gemm2(const float* __restrict__ h2,
                                             const float* __restrict__ W2,
                                             const float* __restrict__ a2s,
                                             const float* __restrict__ a2d,
                                             float* __restrict__ h3,
                                             float* __restrict__ as2,
                                             float* __restrict__ ad2) {
    __shared__ float hs[TM2][HH];        // 8 KiB
    __shared__ float reds[TM2][OUT_CH];
    __shared__ float redd[TM2][OUT_CH];
    int t = threadIdx.x;
    int n0 = blockIdx.x * TM2;
    for (int i = t; i < TM2 * HH; i += 320)
        hs[i >> 8][i & 255] = h2[(size_t)n0 * HH + i];
    __syncthreads();

    int m = t / OUT_CH;   // 0..7
    int c = t % OUT_CH;   // 0..39
    float acc = 0.f;
    for (int k = 0; k < HH; k += 4) {
        float4 hv = *reinterpret_cast<const float4*>(&hs[m][k]);
        acc = fmaf(hv.x, W2[(k + 0) * OUT_CH + c], acc);
        acc = fmaf(hv.y, W2[(k + 1) * OUT_CH + c], acc);
        acc = fmaf(hv.z, W2[(k + 2) * OUT_CH + c], acc);
        acc = fmaf(hv.w, W2[(k + 3) * OUT_CH + c], acc);
    }
    int n = n0 + m;
    h3[(size_t)n * OUT_CH + c] = acc;
    reds[m][c] = acc * a2s[c];
    redd[m][c] = acc * a2d[c];
    __syncthreads();
    if (t < TM2) {
        float ss = 0.f, sd = 0.f;
        for (int i = 0; i < OUT_CH; i++) { ss += reds[t][i]; sd += redd[t][i]; }
        as2[n0 + t] = ss;
        ad2[n0 + t] = sd;
    }
}

// ---------------- Layer 2 attention + aggregate + bias + log_softmax ----------------

__global__ __launch_bounds__(64) void aggr2(const float* __restrict__ h3,
                                            const float* __restrict__ as2,
                                            const float* __restrict__ ad2,
                                            const float* __restrict__ b2,
                                            const int* __restrict__ offs,
                                            const int* __restrict__ csr,
                                            float* __restrict__ out) {
    int d = blockIdx.x;
    int t = threadIdx.x;
    int start = offs[d];
    int deg = offs[d + 1] - start;
    float adv = ad2[d];

    float m_l = -1e30f, s_l = 0.f;
    for (int base = 0; base < deg; base += 64) {
        int jj = base + t;
        if (jj < deg) {
            int s = csr[start + jj];
            float v = as2[s] + adv;
            v = (v > 0.f) ? v : NEG * v;
            float nm = fmaxf(m_l, v);
            s_l = s_l * __expf(m_l - nm) + __expf(v - nm);
            m_l = nm;
        }
    }
    #pragma unroll
    for (int off = 32; off >= 1; off >>= 1) {
        float m_o = __shfl_xor(m_l, off);
        float s_o = __shfl_xor(s_l, off);
        float nm = fmaxf(m_l, m_o);
        s_l = s_l * __expf(m_l - nm) + s_o * __expf(m_o - nm);
        m_l = nm;
    }
    float inv = 1.0f / (s_l + 1e-16f);

    __shared__ float wbuf[64];
    __shared__ int   sbuf[64];
    float acc = 0.f;
    for (int base = 0; base < deg; base += 64) {
        int jj = base + t;
        if (jj < deg) {
            int s = csr[start + jj];
            float v = as2[s] + adv;
            v = (v > 0.f) ? v : NEG * v;
            wbuf[t] = __expf(v - m_l) * inv;
            sbuf[t] = s;
        }
        __syncthreads();
        int lim = deg - base; if (lim > 64) lim = 64;
        if (t < OUT_CH) {
            for (int j2 = 0; j2 < lim; j2++)
                acc = fmaf(h3[(size_t)sbuf[j2] * OUT_CH + t], wbuf[j2], acc);
        }
        __syncthreads();
    }

    float r = (t < OUT_CH) ? (acc + b2[t]) : -1e30f;
    float mx = r;
    #pragma unroll
    for (int off = 32; off >= 1; off >>= 1) mx = fmaxf(mx, __shfl_xor(mx, off));
    float ex = (t < OUT_CH) ? __expf(r - mx) : 0.f;
    float se = ex;
    #pragma unroll
    for (int off = 32; off >= 1; off >>= 1) se += __shfl_xor(se, off);
    if (t < OUT_CH) out[(size_t)d * OUT_CH + t] = r - mx - __logf(se);
}

// ---------------- host launcher ----------------

extern "C" void kernel_launch(void* const* d_in, const int* in_sizes, int n_in,
                              void* d_out, int out_size, void* d_ws, size_t ws_size,
                              hipStream_t stream) {
    const float* x   = (const float*)d_in[0];
    const int*   ei  = (const int*)  d_in[1];
    const float* W1  = (const float*)d_in[2];
    const float* a1s = (const float*)d_in[3];
    const float* a1d = (const float*)d_in[4];
    const float* b1  = (const float*)d_in[5];
    const float* W2  = (const float*)d_in[6];
    const float* a2s = (const float*)d_in[7];
    const float* a2d = (const float*)d_in[8];
    const float* b2  = (const float*)d_in[9];
    float* out = (float*)d_out;

    char* p = (char*)d_ws;
    auto alloc = [&](size_t bytes) {
        char* r = p;
        p += (bytes + 255) & ~(size_t)255;
        return r;
    };
    float* h1   = (float*)alloc((size_t)N_NODES * HH * 4);
    float* h2   = (float*)alloc((size_t)N_NODES * HH * 4);
    float* h3   = (float*)alloc((size_t)N_NODES * OUT_CH * 4);
    float* as1  = (float*)alloc((size_t)N_NODES * HEADS * 4);
    float* ad1  = (float*)alloc((size_t)N_NODES * HEADS * 4);
    float* as2v = (float*)alloc((size_t)N_NODES * 4);
    float* ad2v = (float*)alloc((size_t)N_NODES * 4);
    int* deg    = (int*)alloc((size_t)N_NODES * 4);
    int* cursor = (int*)alloc((size_t)N_NODES * 4);
    int* offs   = (int*)alloc((size_t)(N_NODES + 1) * 4);
    int* csr    = (int*)alloc((size_t)E_TOT * 4);

    // zero deg+cursor (they are adjacent allocations but pad-separated; zero both)
    zero_kernel<<<(N_NODES + 255) / 256, 256, 0, stream>>>(deg, N_NODES);
    zero_kernel<<<(N_NODES + 255) / 256, 256, 0, stream>>>(cursor, N_NODES);

    hist_kernel<<<(E_TOT + 255) / 256, 256, 0, stream>>>(ei, deg);
    scan_kernel<<<1, 1024, 0, stream>>>(deg, offs);
    scatter_kernel<<<(E_TOT + 255) / 256, 256, 0, stream>>>(ei, offs, cursor, csr);

    gemm1<<<N_NODES / TM1, 256, 0, stream>>>(x, W1, a1s, a1d, h1, as1, ad1);
    aggr1<<<N_NODES, 256, 0, stream>>>(h1, as1, ad1, b1, offs, csr, h2);
    gemm2<<<N_NODES / TM2, 320, 0, stream>>>(h2, W2, a2s, a2d, h3, as2v, ad2v);
    aggr2<<<N_NODES, 64, 0, stream>>>(h3, as2v, ad2v, b2, offs, csr, out);
}

// Round 2
// 293.236 us; speedup vs baseline: 1.0722x; 1.0722x over previous
//
#include <hip/hip_runtime.h>
#include <math.h>

#define N_NODES 20000
#define E_RAW   320000
#define E_TOT   (E_RAW + N_NODES)
#define IN_CH   256
#define HEADS   8
#define HID     32
#define HH      (HEADS*HID)   // 256
#define OUT_CH  40
#define NEG     0.2f

// ---------------- CSR build ----------------

__global__ void zero2_kernel(int* a, int* b, int n) {
    int i = blockIdx.x * 256 + threadIdx.x;
    if (i < n) { a[i] = 0; b[i] = 0; }
}

__global__ void hist_kernel(const int* __restrict__ ei, int* __restrict__ deg) {
    int e = blockIdx.x * 256 + threadIdx.x;
    if (e >= E_TOT) return;
    int d = (e < E_RAW) ? ei[E_RAW + e] : (e - E_RAW);
    atomicAdd(&deg[d], 1);
}

__global__ __launch_bounds__(1024) void scan_kernel(const int* __restrict__ deg,
                                                    int* __restrict__ offs) {
    __shared__ int part[1024];
    int t = threadIdx.x;
    const int chunk = (N_NODES + 1023) / 1024;  // 20
    int begin = t * chunk;
    int end = begin + chunk; if (end > N_NODES) end = N_NODES;
    if (begin > N_NODES) begin = N_NODES;
    int s = 0;
    for (int i = begin; i < end; i++) s += deg[i];
    part[t] = s;
    __syncthreads();
    for (int off = 1; off < 1024; off <<= 1) {
        int v = (t >= off) ? part[t - off] : 0;
        __syncthreads();
        part[t] += v;
        __syncthreads();
    }
    int run = (t == 0) ? 0 : part[t - 1];
    for (int i = begin; i < end; i++) { offs[i] = run; run += deg[i]; }
    if (t == 1023) offs[N_NODES] = part[1023];
}

__global__ void scatter_kernel(const int* __restrict__ ei, const int* __restrict__ offs,
                               int* __restrict__ cursor, int* __restrict__ csr) {
    int e = blockIdx.x * 256 + threadIdx.x;
    if (e >= E_TOT) return;
    int s, d;
    if (e < E_RAW) { s = ei[e]; d = ei[E_RAW + e]; }
    else           { s = e - E_RAW; d = s; }
    int pos = atomicAdd(&cursor[d], 1);
    csr[offs[d] + pos] = s;
}

// ---------------- Layer 1 GEMM + alpha (tiled, register-blocked) ----------------
// 64x64 output tile, 256 threads, 4x4 acc/thread. K staged in 64-chunks.
// xsT is x-tile transposed [k][n] so a-frag is a contiguous float4.

#define BM 64
#define BN 64
#define BK 64
__global__ __launch_bounds__(256, 4) void gemm1(const float* __restrict__ x,
                                                const float* __restrict__ W1,
                                                const float* __restrict__ a1s,
                                                const float* __restrict__ a1d,
                                                float* __restrict__ h1,
                                                float* __restrict__ as1,
                                                float* __restrict__ ad1) {
    __shared__ float xsT[BK][BM + 4];   // 17 KiB
    __shared__ float ws[BK][BN + 4];    // 17 KiB
    int t = threadIdx.x;
    int bm = blockIdx.x >> 2;
    int bn = blockIdx.x & 3;
    int n0 = bm * BM;
    int c0 = bn * BN;
    int lr  = t >> 4;          // 0..15
    int tc  = t & 15;          // 0..15
    int lc4 = tc * 4;          // 0..60

    float acc[4][4];
    #pragma unroll
    for (int i = 0; i < 4; i++)
        #pragma unroll
        for (int j = 0; j < 4; j++) acc[i][j] = 0.f;

    for (int k0 = 0; k0 < IN_CH; k0 += BK) {
        // stage x rows (transposed into xsT)
        #pragma unroll
        for (int i = 0; i < 4; i++) {
            int nl = lr + 16 * i;
            int n = n0 + nl;
            float4 v = (n < N_NODES)
                ? *reinterpret_cast<const float4*>(&x[(size_t)n * IN_CH + k0 + lc4])
                : make_float4(0.f, 0.f, 0.f, 0.f);
            xsT[lc4 + 0][nl] = v.x;
            xsT[lc4 + 1][nl] = v.y;
            xsT[lc4 + 2][nl] = v.z;
            xsT[lc4 + 3][nl] = v.w;
        }
        // stage W rows
        #pragma unroll
        for (int i = 0; i < 4; i++) {
            int kl = lr + 16 * i;
            *reinterpret_cast<float4*>(&ws[kl][lc4]) =
                *reinterpret_cast<const float4*>(&W1[(size_t)(k0 + kl) * HH + c0 + lc4]);
        }
        __syncthreads();

        #pragma unroll 8
        for (int kk = 0; kk < BK; kk++) {
            float4 a = *reinterpret_cast<const float4*>(&xsT[kk][lr * 4]);
            float4 b = *reinterpret_cast<const float4*>(&ws[kk][lc4]);
            float av[4] = {a.x, a.y, a.z, a.w};
            float bv[4] = {b.x, b.y, b.z, b.w};
            #pragma unroll
            for (int i = 0; i < 4; i++)
                #pragma unroll
                for (int j = 0; j < 4; j++)
                    acc[i][j] = fmaf(av[i], bv[j], acc[i][j]);
        }
        __syncthreads();
    }

    // epilogue: store h1 + fused alpha head-reductions
    float a_s[4], a_d[4];
    #pragma unroll
    for (int j = 0; j < 4; j++) {
        a_s[j] = a1s[c0 + lc4 + j];
        a_d[j] = a1d[c0 + lc4 + j];
    }
    int head = (c0 >> 5) + (tc >> 3);   // this thread's cols live in one head
    #pragma unroll
    for (int i = 0; i < 4; i++) {
        int n = n0 + lr * 4 + i;
        if (n < N_NODES) {
            *reinterpret_cast<float4*>(&h1[(size_t)n * HH + c0 + lc4]) =
                make_float4(acc[i][0], acc[i][1], acc[i][2], acc[i][3]);
        }
        float vs = acc[i][0] * a_s[0] + acc[i][1] * a_s[1] +
                   acc[i][2] * a_s[2] + acc[i][3] * a_s[3];
        float vd = acc[i][0] * a_d[0] + acc[i][1] * a_d[1] +
                   acc[i][2] * a_d[2] + acc[i][3] * a_d[3];
        vs += __shfl_xor(vs, 1); vs += __shfl_xor(vs, 2); vs += __shfl_xor(vs, 4);
        vd += __shfl_xor(vd, 1); vd += __shfl_xor(vd, 2); vd += __shfl_xor(vd, 4);
        if ((tc & 7) == 0 && n < N_NODES) {
            as1[n * HEADS + head] = vs;
            ad1[n * HEADS + head] = vd;
        }
    }
}

// ---------------- Layer 1 attention + aggregate + bias + ELU ----------------

__global__ __launch_bounds__(256) void aggr1(const float* __restrict__ h1,
                                             const float* __restrict__ as1,
                                             const float* __restrict__ ad1,
                                             const float* __restrict__ b1,
                                             const int* __restrict__ offs,
                                             const int* __restrict__ csr,
                                             float* __restrict__ h2) {
    int d = blockIdx.x;
    int t = threadIdx.x;
    int start = offs[d];
    int deg = offs[d + 1] - start;
    int j = t & 31;      // edge slot
    int h = t >> 5;      // head (also the head of channel c=t)

    float adv = ad1[d * HEADS + h];

    // phase 1: online softmax stats (max & sum) per head
    float m_l = -1e30f, s_l = 0.f;
    for (int base = 0; base < deg; base += 32) {
        int jj = base + j;
        if (jj < deg) {
            int s = csr[start + jj];
            float v = as1[s * HEADS + h] + adv;
            v = (v > 0.f) ? v : NEG * v;
            float nm = fmaxf(m_l, v);
            s_l = s_l * __expf(m_l - nm) + __expf(v - nm);
            m_l = nm;
        }
    }
    #pragma unroll
    for (int off = 16; off >= 1; off >>= 1) {
        float m_o = __shfl_xor(m_l, off);
        float s_o = __shfl_xor(s_l, off);
        float nm = fmaxf(m_l, m_o);
        s_l = s_l * __expf(m_l - nm) + s_o * __expf(m_o - nm);
        m_l = nm;
    }

    __shared__ float mh[HEADS], sh[HEADS];
    __shared__ float wbuf[32][HEADS + 1];
    __shared__ int   sbuf[32];
    if (j == 0) { mh[h] = m_l; sh[h] = s_l; }
    __syncthreads();

    float mhv = mh[h];
    float inv = 1.0f / (sh[h] + 1e-16f);

    float acc = 0.f;
    int c = t;
    for (int base = 0; base < deg; base += 32) {
        int jj = base + j;
        if (jj < deg) {
            int s = csr[start + jj];
            float v = as1[s * HEADS + h] + adv;
            v = (v > 0.f) ? v : NEG * v;
            wbuf[j][h] = __expf(v - mhv) * inv;
            if (h == 0) sbuf[j] = s;
        }
        __syncthreads();
        int lim = deg - base; if (lim > 32) lim = 32;
        for (int j2 = 0; j2 < lim; j2++) {
            int s = sbuf[j2];
            acc = fmaf(h1[(size_t)s * HH + c], wbuf[j2][h], acc);
        }
        __syncthreads();
    }

    float r = acc + b1[c];
    r = (r > 0.f) ? r : (__expf(r) - 1.f);   // ELU
    h2[(size_t)d * HH + c] = r;
}

// ---------------- Layer 2 GEMM + alpha ----------------

#define TM2 8
__global__ __launch_bounds__(320) void gemm2(const float* __restrict__ h2,
                                             const float* __restrict__ W2,
                                             const float* __restrict__ a2s,
                                             const float* __restrict__ a2d,
                                             float* __restrict__ h3,
                                             float* __restrict__ as2,
                                             float* __restrict__ ad2) {
    __shared__ float hs[TM2][HH];        // 8 KiB
    __shared__ float reds[TM2][OUT_CH];
    __shared__ float redd[TM2][OUT_CH];
    int t = threadIdx.x;
    int n0 = blockIdx.x * TM2;
    for (int i = t; i < TM2 * HH; i += 320)
        hs[i >> 8][i & 255] = h2[(size_t)n0 * HH + i];
    __syncthreads();

    int m = t / OUT_CH;   // 0..7
    int c = t % OUT_CH;   // 0..39
    float acc = 0.f;
    for (int k = 0; k < HH; k += 4) {
        float4 hv = *reinterpret_cast<const float4*>(&hs[m][k]);
        acc = fmaf(hv.x, W2[(k + 0) * OUT_CH + c], acc);
        acc = fmaf(hv.y, W2[(k + 1) * OUT_CH + c], acc);
        acc = fmaf(hv.z, W2[(k + 2) * OUT_CH + c], acc);
        acc = fmaf(hv.w, W2[(k + 3) * OUT_CH + c], acc);
    }
    int n = n0 + m;
    h3[(size_t)n * OUT_CH + c] = acc;
    reds[m][c] = acc * a2s[c];
    redd[m][c] = acc * a2d[c];
    __syncthreads();
    if (t < TM2) {
        float ss = 0.f, sd = 0.f;
        for (int i = 0; i < OUT_CH; i++) { ss += reds[t][i]; sd += redd[t][i]; }
        as2[n0 + t] = ss;
        ad2[n0 + t] = sd;
    }
}

// ---------------- Layer 2 attention + aggregate + bias + log_softmax ----------------

__global__ __launch_bounds__(64) void aggr2(const float* __restrict__ h3,
                                            const float* __restrict__ as2,
                                            const float* __restrict__ ad2,
                                            const float* __restrict__ b2,
                                            const int* __restrict__ offs,
                                            const int* __restrict__ csr,
                                            float* __restrict__ out) {
    int d = blockIdx.x;
    int t = threadIdx.x;
    int start = offs[d];
    int deg = offs[d + 1] - start;
    float adv = ad2[d];

    float m_l = -1e30f, s_l = 0.f;
    for (int base = 0; base < deg; base += 64) {
        int jj = base + t;
        if (jj < deg) {
            int s = csr[start + jj];
            float v = as2[s] + adv;
            v = (v > 0.f) ? v : NEG * v;
            float nm = fmaxf(m_l, v);
            s_l = s_l * __expf(m_l - nm) + __expf(v - nm);
            m_l = nm;
        }
    }
    #pragma unroll
    for (int off = 32; off >= 1; off >>= 1) {
        float m_o = __shfl_xor(m_l, off);
        float s_o = __shfl_xor(s_l, off);
        float nm = fmaxf(m_l, m_o);
        s_l = s_l * __expf(m_l - nm) + s_o * __expf(m_o - nm);
        m_l = nm;
    }
    float inv = 1.0f / (s_l + 1e-16f);

    __shared__ float wbuf[64];
    __shared__ int   sbuf[64];
    float acc = 0.f;
    for (int base = 0; base < deg; base += 64) {
        int jj = base + t;
        if (jj < deg) {
            int s = csr[start + jj];
            float v = as2[s] + adv;
            v = (v > 0.f) ? v : NEG * v;
            wbuf[t] = __expf(v - m_l) * inv;
            sbuf[t] = s;
        }
        __syncthreads();
        int lim = deg - base; if (lim > 64) lim = 64;
        if (t < OUT_CH) {
            for (int j2 = 0; j2 < lim; j2++)
                acc = fmaf(h3[(size_t)sbuf[j2] * OUT_CH + t], wbuf[j2], acc);
        }
        __syncthreads();
    }

    float r = (t < OUT_CH) ? (acc + b2[t]) : -1e30f;
    float mx = r;
    #pragma unroll
    for (int off = 32; off >= 1; off >>= 1) mx = fmaxf(mx, __shfl_xor(mx, off));
    float ex = (t < OUT_CH) ? __expf(r - mx) : 0.f;
    float se = ex;
    #pragma unroll
    for (int off = 32; off >= 1; off >>= 1) se += __shfl_xor(se, off);
    if (t < OUT_CH) out[(size_t)d * OUT_CH + t] = r - mx - __logf(se);
}

// ---------------- host launcher ----------------

extern "C" void kernel_launch(void* const* d_in, const int* in_sizes, int n_in,
                              void* d_out, int out_size, void* d_ws, size_t ws_size,
                              hipStream_t stream) {
    const float* x   = (const float*)d_in[0];
    const int*   ei  = (const int*)  d_in[1];
    const float* W1  = (const float*)d_in[2];
    const float* a1s = (const float*)d_in[3];
    const float* a1d = (const float*)d_in[4];
    const float* b1  = (const float*)d_in[5];
    const float* W2  = (const float*)d_in[6];
    const float* a2s = (const float*)d_in[7];
    const float* a2d = (const float*)d_in[8];
    const float* b2  = (const float*)d_in[9];
    float* out = (float*)d_out;

    char* p = (char*)d_ws;
    auto alloc = [&](size_t bytes) {
        char* r = p;
        p += (bytes + 255) & ~(size_t)255;
        return r;
    };
    float* h1   = (float*)alloc((size_t)N_NODES * HH * 4);
    float* h2   = (float*)alloc((size_t)N_NODES * HH * 4);
    float* h3   = (float*)alloc((size_t)N_NODES * OUT_CH * 4);
    float* as1  = (float*)alloc((size_t)N_NODES * HEADS * 4);
    float* ad1  = (float*)alloc((size_t)N_NODES * HEADS * 4);
    float* as2v = (float*)alloc((size_t)N_NODES * 4);
    float* ad2v = (float*)alloc((size_t)N_NODES * 4);
    int* deg    = (int*)alloc((size_t)N_NODES * 4);
    int* cursor = (int*)alloc((size_t)N_NODES * 4);
    int* offs   = (int*)alloc((size_t)(N_NODES + 1) * 4);
    int* csr    = (int*)alloc((size_t)E_TOT * 4);

    zero2_kernel<<<(N_NODES + 255) / 256, 256, 0, stream>>>(deg, cursor, N_NODES);
    hist_kernel<<<(E_TOT + 255) / 256, 256, 0, stream>>>(ei, deg);
    scan_kernel<<<1, 1024, 0, stream>>>(deg, offs);
    scatter_kernel<<<(E_TOT + 255) / 256, 256, 0, stream>>>(ei, offs, cursor, csr);

    gemm1<<<dim3(313 * 4), 256, 0, stream>>>(x, W1, a1s, a1d, h1, as1, ad1);
    aggr1<<<N_NODES, 256, 0, stream>>>(h1, as1, ad1, b1, offs, csr, h2);
    gemm2<<<N_NODES / TM2, 320, 0, stream>>>(h2, W2, a2s, a2d, h3, as2v, ad2v);
    aggr2<<<N_NODES, 64, 0, stream>>>(h3, as2v, ad2v, b2, offs, csr, out);
}

// Round 3
// 283.958 us; speedup vs baseline: 1.1072x; 1.0327x over previous
//
#include <hip/hip_runtime.h>
#include <math.h>

#define N_NODES 20000
#define E_RAW   320000
#define E_TOT   (E_RAW + N_NODES)
#define IN_CH   256
#define HEADS   8
#define HID     32
#define HH      (HEADS*HID)   // 256
#define OUT_CH  40
#define NEG     0.2f

// bf16 helpers (bit-level, round-to-nearest-even; values are finite)
__device__ __forceinline__ unsigned short f2bf(float f) {
    unsigned int u = __float_as_uint(f);
    unsigned int r = (u + 0x7FFFu + ((u >> 16) & 1u)) >> 16;
    return (unsigned short)r;
}
__device__ __forceinline__ float bf2f(unsigned short h) {
    return __uint_as_float(((unsigned int)h) << 16);
}

// ---------------- CSR build ----------------

__global__ void zero2_kernel(int* a, int* b, int n) {
    int i = blockIdx.x * 256 + threadIdx.x;
    if (i < n) { a[i] = 0; b[i] = 0; }
}

__global__ void hist_kernel(const int* __restrict__ ei, int* __restrict__ deg) {
    int e = blockIdx.x * 256 + threadIdx.x;
    if (e >= E_TOT) return;
    int d = (e < E_RAW) ? ei[E_RAW + e] : (e - E_RAW);
    atomicAdd(&deg[d], 1);
}

__global__ __launch_bounds__(1024) void scan_kernel(const int* __restrict__ deg,
                                                    int* __restrict__ offs) {
    __shared__ int part[1024];
    int t = threadIdx.x;
    const int chunk = (N_NODES + 1023) / 1024;  // 20
    int begin = t * chunk;
    int end = begin + chunk; if (end > N_NODES) end = N_NODES;
    if (begin > N_NODES) begin = N_NODES;
    int s = 0;
    for (int i = begin; i < end; i++) s += deg[i];
    part[t] = s;
    __syncthreads();
    for (int off = 1; off < 1024; off <<= 1) {
        int v = (t >= off) ? part[t - off] : 0;
        __syncthreads();
        part[t] += v;
        __syncthreads();
    }
    int run = (t == 0) ? 0 : part[t - 1];
    for (int i = begin; i < end; i++) { offs[i] = run; run += deg[i]; }
    if (t == 1023) offs[N_NODES] = part[1023];
}

__global__ void scatter_kernel(const int* __restrict__ ei, const int* __restrict__ offs,
                               int* __restrict__ cursor, int* __restrict__ csr) {
    int e = blockIdx.x * 256 + threadIdx.x;
    if (e >= E_TOT) return;
    int s, d;
    if (e < E_RAW) { s = ei[e]; d = ei[E_RAW + e]; }
    else           { s = e - E_RAW; d = s; }
    int pos = atomicAdd(&cursor[d], 1);
    csr[offs[d] + pos] = s;
}

// ---------------- Layer 1 GEMM + alpha (tiled, register-blocked) ----------------
// 64x64 output tile, 256 threads, 4x4 acc/thread. K staged in 64-chunks.
// h1 is written as bf16 (gather payload); alphas computed from fp32 accs.

#define BM 64
#define BN 64
#define BK 64
__global__ __launch_bounds__(256, 4) void gemm1(const float* __restrict__ x,
                                                const float* __restrict__ W1,
                                                const float* __restrict__ a1s,
                                                const float* __restrict__ a1d,
                                                unsigned short* __restrict__ h1b,
                                                float* __restrict__ as1,
                                                float* __restrict__ ad1) {
    __shared__ float xsT[BK][BM + 4];   // 17 KiB
    __shared__ float ws[BK][BN + 4];    // 17 KiB
    int t = threadIdx.x;
    int bm = blockIdx.x >> 2;
    int bn = blockIdx.x & 3;
    int n0 = bm * BM;
    int c0 = bn * BN;
    int lr  = t >> 4;          // 0..15
    int tc  = t & 15;          // 0..15
    int lc4 = tc * 4;          // 0..60

    float acc[4][4];
    #pragma unroll
    for (int i = 0; i < 4; i++)
        #pragma unroll
        for (int j = 0; j < 4; j++) acc[i][j] = 0.f;

    for (int k0 = 0; k0 < IN_CH; k0 += BK) {
        #pragma unroll
        for (int i = 0; i < 4; i++) {
            int nl = lr + 16 * i;
            int n = n0 + nl;
            float4 v = (n < N_NODES)
                ? *reinterpret_cast<const float4*>(&x[(size_t)n * IN_CH + k0 + lc4])
                : make_float4(0.f, 0.f, 0.f, 0.f);
            xsT[lc4 + 0][nl] = v.x;
            xsT[lc4 + 1][nl] = v.y;
            xsT[lc4 + 2][nl] = v.z;
            xsT[lc4 + 3][nl] = v.w;
        }
        #pragma unroll
        for (int i = 0; i < 4; i++) {
            int kl = lr + 16 * i;
            *reinterpret_cast<float4*>(&ws[kl][lc4]) =
                *reinterpret_cast<const float4*>(&W1[(size_t)(k0 + kl) * HH + c0 + lc4]);
        }
        __syncthreads();

        #pragma unroll 8
        for (int kk = 0; kk < BK; kk++) {
            float4 a = *reinterpret_cast<const float4*>(&xsT[kk][lr * 4]);
            float4 b = *reinterpret_cast<const float4*>(&ws[kk][lc4]);
            float av[4] = {a.x, a.y, a.z, a.w};
            float bv[4] = {b.x, b.y, b.z, b.w};
            #pragma unroll
            for (int i = 0; i < 4; i++)
                #pragma unroll
                for (int j = 0; j < 4; j++)
                    acc[i][j] = fmaf(av[i], bv[j], acc[i][j]);
        }
        __syncthreads();
    }

    float a_s[4], a_d[4];
    #pragma unroll
    for (int j = 0; j < 4; j++) {
        a_s[j] = a1s[c0 + lc4 + j];
        a_d[j] = a1d[c0 + lc4 + j];
    }
    int head = (c0 >> 5) + (tc >> 3);   // this thread's 4 cols live in one head
    #pragma unroll
    for (int i = 0; i < 4; i++) {
        int n = n0 + lr * 4 + i;
        if (n < N_NODES) {
            ushort4 pv;
            pv.x = f2bf(acc[i][0]); pv.y = f2bf(acc[i][1]);
            pv.z = f2bf(acc[i][2]); pv.w = f2bf(acc[i][3]);
            *reinterpret_cast<ushort4*>(&h1b[(size_t)n * HH + c0 + lc4]) = pv;
        }
        float vs = acc[i][0] * a_s[0] + acc[i][1] * a_s[1] +
                   acc[i][2] * a_s[2] + acc[i][3] * a_s[3];
        float vd = acc[i][0] * a_d[0] + acc[i][1] * a_d[1] +
                   acc[i][2] * a_d[2] + acc[i][3] * a_d[3];
        vs += __shfl_xor(vs, 1); vs += __shfl_xor(vs, 2); vs += __shfl_xor(vs, 4);
        vd += __shfl_xor(vd, 1); vd += __shfl_xor(vd, 2); vd += __shfl_xor(vd, 4);
        if ((tc & 7) == 0 && n < N_NODES) {
            as1[n * HEADS + head] = vs;
            ad1[n * HEADS + head] = vd;
        }
    }
}

// ---------------- Layer 1 attention + aggregate + bias + ELU ----------------
// h1 gathered as bf16; h2 written as bf16.

__global__ __launch_bounds__(256) void aggr1(const unsigned short* __restrict__ h1b,
                                             const float* __restrict__ as1,
                                             const float* __restrict__ ad1,
                                             const float* __restrict__ b1,
                                             const int* __restrict__ offs,
                                             const int* __restrict__ csr,
                                             unsigned short* __restrict__ h2b) {
    int d = blockIdx.x;
    int t = threadIdx.x;
    int start = offs[d];
    int deg = offs[d + 1] - start;
    int j = t & 31;      // edge slot
    int h = t >> 5;      // head (also head of channel c=t)

    float adv = ad1[d * HEADS + h];

    float m_l = -1e30f, s_l = 0.f;
    for (int base = 0; base < deg; base += 32) {
        int jj = base + j;
        if (jj < deg) {
            int s = csr[start + jj];
            float v = as1[s * HEADS + h] + adv;
            v = (v > 0.f) ? v : NEG * v;
            float nm = fmaxf(m_l, v);
            s_l = s_l * __expf(m_l - nm) + __expf(v - nm);
            m_l = nm;
        }
    }
    #pragma unroll
    for (int off = 16; off >= 1; off >>= 1) {
        float m_o = __shfl_xor(m_l, off);
        float s_o = __shfl_xor(s_l, off);
        float nm = fmaxf(m_l, m_o);
        s_l = s_l * __expf(m_l - nm) + s_o * __expf(m_o - nm);
        m_l = nm;
    }

    __shared__ float mh[HEADS], sh[HEADS];
    __shared__ float wbuf[32][HEADS + 1];
    __shared__ int   sbuf[32];
    if (j == 0) { mh[h] = m_l; sh[h] = s_l; }
    __syncthreads();

    float mhv = mh[h];
    float inv = 1.0f / (sh[h] + 1e-16f);

    float acc = 0.f;
    int c = t;
    for (int base = 0; base < deg; base += 32) {
        int jj = base + j;
        if (jj < deg) {
            int s = csr[start + jj];
            float v = as1[s * HEADS + h] + adv;
            v = (v > 0.f) ? v : NEG * v;
            wbuf[j][h] = __expf(v - mhv) * inv;
            if (h == 0) sbuf[j] = s;
        }
        __syncthreads();
        int lim = deg - base; if (lim > 32) lim = 32;
        for (int j2 = 0; j2 < lim; j2++) {
            int s = sbuf[j2];
            acc = fmaf(bf2f(h1b[(size_t)s * HH + c]), wbuf[j2][h], acc);
        }
        __syncthreads();
    }

    float r = acc + b1[c];
    r = (r > 0.f) ? r : (__expf(r) - 1.f);   // ELU
    h2b[(size_t)d * HH + c] = f2bf(r);
}

// ---------------- Layer 2 GEMM + alpha ----------------

#define TM2 8
__global__ __launch_bounds__(320) void gemm2(const unsigned short* __restrict__ h2b,
                                             const float* __restrict__ W2,
                                             const float* __restrict__ a2s,
                                             const float* __restrict__ a2d,
                                             unsigned short* __restrict__ h3b,
                                             float* __restrict__ as2,
                                             float* __restrict__ ad2) {
    __shared__ float hs[TM2][HH];        // 8 KiB
    __shared__ float reds[TM2][OUT_CH];
    __shared__ float redd[TM2][OUT_CH];
    int t = threadIdx.x;
    int n0 = blockIdx.x * TM2;
    for (int i = t; i < TM2 * HH; i += 320)
        hs[i >> 8][i & 255] = bf2f(h2b[(size_t)n0 * HH + i]);
    __syncthreads();

    int m = t / OUT_CH;   // 0..7
    int c = t % OUT_CH;   // 0..39
    float acc = 0.f;
    for (int k = 0; k < HH; k += 4) {
        float4 hv = *reinterpret_cast<const float4*>(&hs[m][k]);
        acc = fmaf(hv.x, W2[(k + 0) * OUT_CH + c], acc);
        acc = fmaf(hv.y, W2[(k + 1) * OUT_CH + c], acc);
        acc = fmaf(hv.z, W2[(k + 2) * OUT_CH + c], acc);
        acc = fmaf(hv.w, W2[(k + 3) * OUT_CH + c], acc);
    }
    int n = n0 + m;
    h3b[(size_t)n * OUT_CH + c] = f2bf(acc);
    reds[m][c] = acc * a2s[c];
    redd[m][c] = acc * a2d[c];
    __syncthreads();
    if (t < TM2) {
        float ss = 0.f, sd = 0.f;
        for (int i = 0; i < OUT_CH; i++) { ss += reds[t][i]; sd += redd[t][i]; }
        as2[n0 + t] = ss;
        ad2[n0 + t] = sd;
    }
}

// ---------------- Layer 2 attention + aggregate + bias + log_softmax ----------------

__global__ __launch_bounds__(64) void aggr2(const unsigned short* __restrict__ h3b,
                                            const float* __restrict__ as2,
                                            const float* __restrict__ ad2,
                                            const float* __restrict__ b2,
                                            const int* __restrict__ offs,
                                            const int* __restrict__ csr,
                                            float* __restrict__ out) {
    int d = blockIdx.x;
    int t = threadIdx.x;
    int start = offs[d];
    int deg = offs[d + 1] - start;
    float adv = ad2[d];

    float m_l = -1e30f, s_l = 0.f;
    for (int base = 0; base < deg; base += 64) {
        int jj = base + t;
        if (jj < deg) {
            int s = csr[start + jj];
            float v = as2[s] + adv;
            v = (v > 0.f) ? v : NEG * v;
            float nm = fmaxf(m_l, v);
            s_l = s_l * __expf(m_l - nm) + __expf(v - nm);
            m_l = nm;
        }
    }
    #pragma unroll
    for (int off = 32; off >= 1; off >>= 1) {
        float m_o = __shfl_xor(m_l, off);
        float s_o = __shfl_xor(s_l, off);
        float nm = fmaxf(m_l, m_o);
        s_l = s_l * __expf(m_l - nm) + s_o * __expf(m_o - nm);
        m_l = nm;
    }
    float inv = 1.0f / (s_l + 1e-16f);

    __shared__ float wbuf[64];
    __shared__ int   sbuf[64];
    float acc = 0.f;
    for (int base = 0; base < deg; base += 64) {
        int jj = base + t;
        if (jj < deg) {
            int s = csr[start + jj];
            float v = as2[s] + adv;
            v = (v > 0.f) ? v : NEG * v;
            wbuf[t] = __expf(v - m_l) * inv;
            sbuf[t] = s;
        }
        __syncthreads();
        int lim = deg - base; if (lim > 64) lim = 64;
        if (t < OUT_CH) {
            for (int j2 = 0; j2 < lim; j2++)
                acc = fmaf(bf2f(h3b[(size_t)sbuf[j2] * OUT_CH + t]), wbuf[j2], acc);
        }
        __syncthreads();
    }

    float r = (t < OUT_CH) ? (acc + b2[t]) : -1e30f;
    float mx = r;
    #pragma unroll
    for (int off = 32; off >= 1; off >>= 1) mx = fmaxf(mx, __shfl_xor(mx, off));
    float ex = (t < OUT_CH) ? __expf(r - mx) : 0.f;
    float se = ex;
    #pragma unroll
    for (int off = 32; off >= 1; off >>= 1) se += __shfl_xor(se, off);
    if (t < OUT_CH) out[(size_t)d * OUT_CH + t] = r - mx - __logf(se);
}

// ---------------- host launcher ----------------

extern "C" void kernel_launch(void* const* d_in, const int* in_sizes, int n_in,
                              void* d_out, int out_size, void* d_ws, size_t ws_size,
                              hipStream_t stream) {
    const float* x   = (const float*)d_in[0];
    const int*   ei  = (const int*)  d_in[1];
    const float* W1  = (const float*)d_in[2];
    const float* a1s = (const float*)d_in[3];
    const float* a1d = (const float*)d_in[4];
    const float* b1  = (const float*)d_in[5];
    const float* W2  = (const float*)d_in[6];
    const float* a2s = (const float*)d_in[7];
    const float* a2d = (const float*)d_in[8];
    const float* b2  = (const float*)d_in[9];
    float* out = (float*)d_out;

    char* p = (char*)d_ws;
    auto alloc = [&](size_t bytes) {
        char* r = p;
        p += (bytes + 255) & ~(size_t)255;
        return r;
    };
    unsigned short* h1b = (unsigned short*)alloc((size_t)N_NODES * HH * 2);
    unsigned short* h2b = (unsigned short*)alloc((size_t)N_NODES * HH * 2);
    unsigned short* h3b = (unsigned short*)alloc((size_t)N_NODES * OUT_CH * 2);
    float* as1  = (float*)alloc((size_t)N_NODES * HEADS * 4);
    float* ad1  = (float*)alloc((size_t)N_NODES * HEADS * 4);
    float* as2v = (float*)alloc((size_t)N_NODES * 4);
    float* ad2v = (float*)alloc((size_t)N_NODES * 4);
    int* deg    = (int*)alloc((size_t)N_NODES * 4);
    int* cursor = (int*)alloc((size_t)N_NODES * 4);
    int* offs   = (int*)alloc((size_t)(N_NODES + 1) * 4);
    int* csr    = (int*)alloc((size_t)E_TOT * 4);

    zero2_kernel<<<(N_NODES + 255) / 256, 256, 0, stream>>>(deg, cursor, N_NODES);
    hist_kernel<<<(E_TOT + 255) / 256, 256, 0, stream>>>(ei, deg);
    scan_kernel<<<1, 1024, 0, stream>>>(deg, offs);
    scatter_kernel<<<(E_TOT + 255) / 256, 256, 0, stream>>>(ei, offs, cursor, csr);

    gemm1<<<dim3(313 * 4), 256, 0, stream>>>(x, W1, a1s, a1d, h1b, as1, ad1);
    aggr1<<<N_NODES, 256, 0, stream>>>(h1b, as1, ad1, b1, offs, csr, h2b);
    gemm2<<<N_NODES / TM2, 320, 0, stream>>>(h2b, W2, a2s, a2d, h3b, as2v, ad2v);
    aggr2<<<N_NODES, 64, 0, stream>>>(h3b, as2v, ad2v, b2, offs, csr, out);
}

// Round 4
// 282.871 us; speedup vs baseline: 1.1115x; 1.0038x over previous
//
#include <hip/hip_runtime.h>
#include <math.h>

#define N_NODES 20000
#define E_RAW   320000
#define E_TOT   (E_RAW + N_NODES)
#define IN_CH   256
#define HEADS   8
#define HID     32
#define HH      (HEADS*HID)   // 256
#define OUT_CH  40
#define NEG     0.2f

typedef __attribute__((ext_vector_type(8))) short  short8;
typedef __attribute__((ext_vector_type(4))) float  floatx4;

// bf16 helpers (bit-level, round-to-nearest-even; values are finite)
__device__ __forceinline__ unsigned short f2bf(float f) {
    unsigned int u = __float_as_uint(f);
    unsigned int r = (u + 0x7FFFu + ((u >> 16) & 1u)) >> 16;
    return (unsigned short)r;
}
__device__ __forceinline__ float bf2f(unsigned short h) {
    return __uint_as_float(((unsigned int)h) << 16);
}

// ---------------- CSR build ----------------

__global__ void zero2_kernel(int* a, int* b, int n) {
    int i = blockIdx.x * 256 + threadIdx.x;
    if (i < n) { a[i] = 0; b[i] = 0; }
}

__global__ void hist_kernel(const int* __restrict__ ei, int* __restrict__ deg) {
    int e = blockIdx.x * 256 + threadIdx.x;
    if (e >= E_TOT) return;
    int d = (e < E_RAW) ? ei[E_RAW + e] : (e - E_RAW);
    atomicAdd(&deg[d], 1);
}

__global__ __launch_bounds__(1024) void scan_kernel(const int* __restrict__ deg,
                                                    int* __restrict__ offs) {
    __shared__ int part[1024];
    int t = threadIdx.x;
    const int chunk = (N_NODES + 1023) / 1024;  // 20
    int begin = t * chunk;
    int end = begin + chunk; if (end > N_NODES) end = N_NODES;
    if (begin > N_NODES) begin = N_NODES;
    int s = 0;
    for (int i = begin; i < end; i++) s += deg[i];
    part[t] = s;
    __syncthreads();
    for (int off = 1; off < 1024; off <<= 1) {
        int v = (t >= off) ? part[t - off] : 0;
        __syncthreads();
        part[t] += v;
        __syncthreads();
    }
    int run = (t == 0) ? 0 : part[t - 1];
    for (int i = begin; i < end; i++) { offs[i] = run; run += deg[i]; }
    if (t == 1023) offs[N_NODES] = part[1023];
}

__global__ void scatter_kernel(const int* __restrict__ ei, const int* __restrict__ offs,
                               int* __restrict__ cursor, int* __restrict__ csr) {
    int e = blockIdx.x * 256 + threadIdx.x;
    if (e >= E_TOT) return;
    int s, d;
    if (e < E_RAW) { s = ei[e]; d = ei[E_RAW + e]; }
    else           { s = e - E_RAW; d = s; }
    int pos = atomicAdd(&cursor[d], 1);
    csr[offs[d] + pos] = s;
}

// ---------------- Layer 1 GEMM: MFMA bf16 ----------------
// 64(nodes) x 64(cols) tile, 256 threads = 4 waves; wave w owns rows [16w,16w+16)
// and all 64 cols (4 n-tiles of 16). A = x (row-major, bf16 in LDS), B = W1
// staged transposed Bt[n][k]. mfma_f32_16x16x32_bf16:
//   A-frag: m=lane&15, k=(lane>>4)*8+j ; B-frag: n=lane&15, k=(lane>>4)*8+j
//   C/D:    col=lane&15, row=(lane>>4)*4+reg       [m89-verified]
#define G1_LDK 72   // 64 + 8 pad (shorts): row stride 144B -> 2-way bank alias (free)
__global__ __launch_bounds__(256) void gemm1(const float* __restrict__ x,
                                             const float* __restrict__ W1,
                                             unsigned short* __restrict__ h1b) {
    __shared__ unsigned short As[64 * G1_LDK];   // 9 KiB
    __shared__ unsigned short Bt[64 * G1_LDK];   // 9 KiB
    int t    = threadIdx.x;
    int wave = t >> 6;
    int lane = t & 63;
    int ln   = lane & 15;
    int q    = lane >> 4;
    int bm = blockIdx.x >> 2;      // 313 row blocks
    int bn = blockIdx.x & 3;       // 4 col blocks
    int n0 = bm * 64;
    int c0 = bn * 64;

    floatx4 acc[4];
    #pragma unroll
    for (int f = 0; f < 4; f++) acc[f] = (floatx4){0.f, 0.f, 0.f, 0.f};

    int srow = t >> 4;            // 0..15
    int scol = t & 15;            // 0..15

    for (int kc = 0; kc < IN_CH; kc += 64) {
        // stage x -> As (bf16), 64 rows x 64 k
        #pragma unroll
        for (int p = 0; p < 4; p++) {
            int row = srow + p * 16;
            int n = n0 + row;
            float4 v = (n < N_NODES)
                ? *reinterpret_cast<const float4*>(&x[(size_t)n * IN_CH + kc + scol * 4])
                : make_float4(0.f, 0.f, 0.f, 0.f);
            ushort4 pv;
            pv.x = f2bf(v.x); pv.y = f2bf(v.y); pv.z = f2bf(v.z); pv.w = f2bf(v.w);
            *reinterpret_cast<ushort4*>(&As[row * G1_LDK + scol * 4]) = pv;
        }
        // stage W1 -> Bt[n][k] (transposed)
        #pragma unroll
        for (int p = 0; p < 4; p++) {
            int kl = srow + p * 16;
            float4 v = *reinterpret_cast<const float4*>(
                &W1[(size_t)(kc + kl) * HH + c0 + scol * 4]);
            Bt[(scol * 4 + 0) * G1_LDK + kl] = f2bf(v.x);
            Bt[(scol * 4 + 1) * G1_LDK + kl] = f2bf(v.y);
            Bt[(scol * 4 + 2) * G1_LDK + kl] = f2bf(v.z);
            Bt[(scol * 4 + 3) * G1_LDK + kl] = f2bf(v.w);
        }
        __syncthreads();

        #pragma unroll
        for (int ks = 0; ks < 2; ks++) {
            short8 a = *reinterpret_cast<const short8*>(
                &As[(16 * wave + ln) * G1_LDK + ks * 32 + q * 8]);
            #pragma unroll
            for (int f = 0; f < 4; f++) {
                short8 b = *reinterpret_cast<const short8*>(
                    &Bt[(16 * f + ln) * G1_LDK + ks * 32 + q * 8]);
                acc[f] = __builtin_amdgcn_mfma_f32_16x16x32_bf16(a, b, acc[f], 0, 0, 0);
            }
        }
        __syncthreads();
    }

    // store h1 (bf16)
    #pragma unroll
    for (int f = 0; f < 4; f++) {
        #pragma unroll
        for (int r = 0; r < 4; r++) {
            int row = 16 * wave + q * 4 + r;
            int n = n0 + row;
            if (n < N_NODES)
                h1b[(size_t)n * HH + c0 + 16 * f + ln] = f2bf(acc[f][r]);
        }
    }
}

// ---------------- alpha1: as1/ad1 from bf16 h1 ----------------
// block=256 handles 8 nodes; per node: 256 lanes load the row, per-head 32-lane reduce.
__global__ __launch_bounds__(256) void alpha1_kernel(const unsigned short* __restrict__ h1b,
                                                     const float* __restrict__ a1s,
                                                     const float* __restrict__ a1d,
                                                     float* __restrict__ as1,
                                                     float* __restrict__ ad1) {
    int t = threadIdx.x;
    float asc = a1s[t], adc = a1d[t];
    int h = t >> 5;
    #pragma unroll
    for (int r = 0; r < 8; r++) {
        int n = blockIdx.x * 8 + r;
        float v = bf2f(h1b[(size_t)n * HH + t]);
        float vs = v * asc, vd = v * adc;
        #pragma unroll
        for (int off = 16; off >= 1; off >>= 1) {
            vs += __shfl_xor(vs, off);
            vd += __shfl_xor(vd, off);
        }
        if ((t & 31) == 0) {
            as1[n * HEADS + h] = vs;
            ad1[n * HEADS + h] = vd;
        }
    }
}

// ---------------- Layer 1 attention + aggregate + bias + ELU ----------------
// phase 1: 8 heads x 32 edge-slots online softmax stats.
// phase 2: one WAVE per edge (4 waves/block, strided), lane = 4 channels (ushort4).

__global__ __launch_bounds__(256) void aggr1(const unsigned short* __restrict__ h1b,
                                             const float* __restrict__ as1,
                                             const float* __restrict__ ad1,
                                             const float* __restrict__ b1,
                                             const int* __restrict__ offs,
                                             const int* __restrict__ csr,
                                             unsigned short* __restrict__ h2b) {
    int d = blockIdx.x;
    int t = threadIdx.x;
    int start = offs[d];
    int deg = offs[d + 1] - start;
    int wave = t >> 6;
    int lane = t & 63;

    __shared__ float mh[HEADS], sh[HEADS];
    __shared__ float part[4][HH];

    // ---- phase 1: per-head max & denom ----
    {
        int j = t & 31;
        int h = t >> 5;
        float adv = ad1[d * HEADS + h];
        float m_l = -1e30f, s_l = 0.f;
        for (int base = 0; base < deg; base += 32) {
            int jj = base + j;
            if (jj < deg) {
                int s = csr[start + jj];
                float v = as1[s * HEADS + h] + adv;
                v = (v > 0.f) ? v : NEG * v;
                float nm = fmaxf(m_l, v);
                s_l = s_l * __expf(m_l - nm) + __expf(v - nm);
                m_l = nm;
            }
        }
        #pragma unroll
        for (int off = 16; off >= 1; off >>= 1) {
            float m_o = __shfl_xor(m_l, off);
            float s_o = __shfl_xor(s_l, off);
            float nm = fmaxf(m_l, m_o);
            s_l = s_l * __expf(m_l - nm) + s_o * __expf(m_o - nm);
            m_l = nm;
        }
        if (j == 0) { mh[h] = m_l; sh[h] = s_l; }
    }
    __syncthreads();

    // ---- phase 2: wave per edge, lane = 4 channels ----
    int h = lane >> 3;            // channels [lane*4, lane*4+4) all in head lane>>3
    int c4 = lane * 4;
    float adv = ad1[d * HEADS + h];
    float mhv = mh[h];
    float inv = 1.0f / (sh[h] + 1e-16f);

    float acc0 = 0.f, acc1 = 0.f, acc2 = 0.f, acc3 = 0.f;
    for (int jj = wave; jj < deg; jj += 4) {
        int s = csr[start + jj];
        float v = as1[s * HEADS + h] + adv;
        v = (v > 0.f) ? v : NEG * v;
        float w = __expf(v - mhv) * inv;
        ushort4 pv = *reinterpret_cast<const ushort4*>(&h1b[(size_t)s * HH + c4]);
        acc0 = fmaf(bf2f(pv.x), w, acc0);
        acc1 = fmaf(bf2f(pv.y), w, acc1);
        acc2 = fmaf(bf2f(pv.z), w, acc2);
        acc3 = fmaf(bf2f(pv.w), w, acc3);
    }
    *reinterpret_cast<float4*>(&part[wave][c4]) = make_float4(acc0, acc1, acc2, acc3);
    __syncthreads();

    float r = part[0][t] + part[1][t] + part[2][t] + part[3][t] + b1[t];
    r = (r > 0.f) ? r : (__expf(r) - 1.f);   // ELU
    h2b[(size_t)d * HH + t] = f2bf(r);
}

// ---------------- Layer 2 GEMM + alpha ----------------

#define TM2 8
__global__ __launch_bounds__(320) void gemm2(const unsigned short* __restrict__ h2b,
                                             const float* __restrict__ W2,
                                             const float* __restrict__ a2s,
                                             const float* __restrict__ a2d,
                                             unsigned short* __restrict__ h3b,
                                             float* __restrict__ as2,
                                             float* __restrict__ ad2) {
    __shared__ float hs[TM2][HH];        // 8 KiB
    __shared__ float reds[TM2][OUT_CH];
    __shared__ float redd[TM2][OUT_CH];
    int t = threadIdx.x;
    int n0 = blockIdx.x * TM2;
    for (int i = t; i < TM2 * HH; i += 320)
        hs[i >> 8][i & 255] = bf2f(h2b[(size_t)n0 * HH + i]);
    __syncthreads();

    int m = t / OUT_CH;   // 0..7
    int c = t % OUT_CH;   // 0..39
    float acc = 0.f;
    for (int k = 0; k < HH; k += 4) {
        float4 hv = *reinterpret_cast<const float4*>(&hs[m][k]);
        acc = fmaf(hv.x, W2[(k + 0) * OUT_CH + c], acc);
        acc = fmaf(hv.y, W2[(k + 1) * OUT_CH + c], acc);
        acc = fmaf(hv.z, W2[(k + 2) * OUT_CH + c], acc);
        acc = fmaf(hv.w, W2[(k + 3) * OUT_CH + c], acc);
    }
    int n = n0 + m;
    h3b[(size_t)n * OUT_CH + c] = f2bf(acc);
    reds[m][c] = acc * a2s[c];
    redd[m][c] = acc * a2d[c];
    __syncthreads();
    if (t < TM2) {
        float ss = 0.f, sd = 0.f;
        for (int i = 0; i < OUT_CH; i++) { ss += reds[t][i]; sd += redd[t][i]; }
        as2[n0 + t] = ss;
        ad2[n0 + t] = sd;
    }
}

// ---------------- Layer 2 attention + aggregate + log_softmax ----------------
// wave per node (4 nodes/block); edge weights held in registers, moved by shuffles.

__global__ __launch_bounds__(256) void aggr2(const unsigned short* __restrict__ h3b,
                                             const float* __restrict__ as2,
                                             const float* __restrict__ ad2,
                                             const float* __restrict__ b2,
                                             const int* __restrict__ offs,
                                             const int* __restrict__ csr,
                                             float* __restrict__ out) {
    int d = blockIdx.x * 4 + (threadIdx.x >> 6);
    int lane = threadIdx.x & 63;
    int start = offs[d];
    int deg = offs[d + 1] - start;
    float adv = ad2[d];

    float m_l = -1e30f, s_l = 0.f;
    for (int base = 0; base < deg; base += 64) {
        int jj = base + lane;
        if (jj < deg) {
            int s = csr[start + jj];
            float v = as2[s] + adv;
            v = (v > 0.f) ? v : NEG * v;
            float nm = fmaxf(m_l, v);
            s_l = s_l * __expf(m_l - nm) + __expf(v - nm);
            m_l = nm;
        }
    }
    #pragma unroll
    for (int off = 32; off >= 1; off >>= 1) {
        float m_o = __shfl_xor(m_l, off);
        float s_o = __shfl_xor(s_l, off);
        float nm = fmaxf(m_l, m_o);
        s_l = s_l * __expf(m_l - nm) + s_o * __expf(m_o - nm);
        m_l = nm;
    }
    float inv = 1.0f / (s_l + 1e-16f);

    float a0 = 0.f, a1 = 0.f, a2 = 0.f, a3 = 0.f;
    for (int base = 0; base < deg; base += 64) {
        int jj = base + lane;
        int s_reg = 0; float w_reg = 0.f;
        if (jj < deg) {
            s_reg = csr[start + jj];
            float v = as2[s_reg] + adv;
            v = (v > 0.f) ? v : NEG * v;
            w_reg = __expf(v - m_l) * inv;
        }
        int lim = deg - base; if (lim > 64) lim = 64;
        int j2 = 0;
        for (; j2 + 3 < lim; j2 += 4) {
            int   s0 = __shfl(s_reg, j2 + 0), s1 = __shfl(s_reg, j2 + 1);
            int   s2 = __shfl(s_reg, j2 + 2), s3 = __shfl(s_reg, j2 + 3);
            float w0 = __shfl(w_reg, j2 + 0), w1 = __shfl(w_reg, j2 + 1);
            float w2 = __shfl(w_reg, j2 + 2), w3 = __shfl(w_reg, j2 + 3);
            if (lane < OUT_CH) {
                a0 = fmaf(bf2f(h3b[(size_t)s0 * OUT_CH + lane]), w0, a0);
                a1 = fmaf(bf2f(h3b[(size_t)s1 * OUT_CH + lane]), w1, a1);
                a2 = fmaf(bf2f(h3b[(size_t)s2 * OUT_CH + lane]), w2, a2);
                a3 = fmaf(bf2f(h3b[(size_t)s3 * OUT_CH + lane]), w3, a3);
            }
        }
        for (; j2 < lim; j2++) {
            int   s0 = __shfl(s_reg, j2);
            float w0 = __shfl(w_reg, j2);
            if (lane < OUT_CH)
                a0 = fmaf(bf2f(h3b[(size_t)s0 * OUT_CH + lane]), w0, a0);
        }
    }

    float r = (lane < OUT_CH) ? (a0 + a1 + a2 + a3 + b2[lane]) : -1e30f;
    float mx = r;
    #pragma unroll
    for (int off = 32; off >= 1; off >>= 1) mx = fmaxf(mx, __shfl_xor(mx, off));
    float ex = (lane < OUT_CH) ? __expf(r - mx) : 0.f;
    float se = ex;
    #pragma unroll
    for (int off = 32; off >= 1; off >>= 1) se += __shfl_xor(se, off);
    if (lane < OUT_CH) out[(size_t)d * OUT_CH + lane] = r - mx - __logf(se);
}

// ---------------- host launcher ----------------

extern "C" void kernel_launch(void* const* d_in, const int* in_sizes, int n_in,
                              void* d_out, int out_size, void* d_ws, size_t ws_size,
                              hipStream_t stream) {
    const float* x   = (const float*)d_in[0];
    const int*   ei  = (const int*)  d_in[1];
    const float* W1  = (const float*)d_in[2];
    const float* a1s = (const float*)d_in[3];
    const float* a1d = (const float*)d_in[4];
    const float* b1  = (const float*)d_in[5];
    const float* W2  = (const float*)d_in[6];
    const float* a2s = (const float*)d_in[7];
    const float* a2d = (const float*)d_in[8];
    const float* b2  = (const float*)d_in[9];
    float* out = (float*)d_out;

    char* p = (char*)d_ws;
    auto alloc = [&](size_t bytes) {
        char* r = p;
        p += (bytes + 255) & ~(size_t)255;
        return r;
    };
    unsigned short* h1b = (unsigned short*)alloc((size_t)N_NODES * HH * 2);
    unsigned short* h2b = (unsigned short*)alloc((size_t)N_NODES * HH * 2);
    unsigned short* h3b = (unsigned short*)alloc((size_t)N_NODES * OUT_CH * 2);
    float* as1  = (float*)alloc((size_t)N_NODES * HEADS * 4);
    float* ad1  = (float*)alloc((size_t)N_NODES * HEADS * 4);
    float* as2v = (float*)alloc((size_t)N_NODES * 4);
    float* ad2v = (float*)alloc((size_t)N_NODES * 4);
    int* deg    = (int*)alloc((size_t)N_NODES * 4);
    int* cursor = (int*)alloc((size_t)N_NODES * 4);
    int* offs   = (int*)alloc((size_t)(N_NODES + 1) * 4);
    int* csr    = (int*)alloc((size_t)E_TOT * 4);

    zero2_kernel<<<(N_NODES + 255) / 256, 256, 0, stream>>>(deg, cursor, N_NODES);
    hist_kernel<<<(E_TOT + 255) / 256, 256, 0, stream>>>(ei, deg);
    scan_kernel<<<1, 1024, 0, stream>>>(deg, offs);
    scatter_kernel<<<(E_TOT + 255) / 256, 256, 0, stream>>>(ei, offs, cursor, csr);

    gemm1<<<dim3(313 * 4), 256, 0, stream>>>(x, W1, h1b);
    alpha1_kernel<<<N_NODES / 8, 256, 0, stream>>>(h1b, a1s, a1d, as1, ad1);
    aggr1<<<N_NODES, 256, 0, stream>>>(h1b, as1, ad1, b1, offs, csr, h2b);
    gemm2<<<N_NODES / TM2, 320, 0, stream>>>(h2b, W2, a2s, a2d, h3b, as2v, ad2v);
    aggr2<<<N_NODES / 4, 256, 0, stream>>>(h3b, as2v, ad2v, b2, offs, csr, out);
}

// Round 5
// 276.186 us; speedup vs baseline: 1.1384x; 1.0242x over previous
//
#include <hip/hip_runtime.h>
#include <math.h>

#define N_NODES 20000
#define E_RAW   320000
#define E_TOT   (E_RAW + N_NODES)
#define IN_CH   256
#define HEADS   8
#define HID     32
#define HH      (HEADS*HID)   // 256
#define OUT_CH  40
#define NEG     0.2f

typedef __attribute__((ext_vector_type(8))) short  short8;
typedef __attribute__((ext_vector_type(4))) float  floatx4;

// bf16 helpers (bit-level, round-to-nearest-even; values are finite)
__device__ __forceinline__ unsigned short f2bf(float f) {
    unsigned int u = __float_as_uint(f);
    unsigned int r = (u + 0x7FFFu + ((u >> 16) & 1u)) >> 16;
    return (unsigned short)r;
}
__device__ __forceinline__ float bf2f(unsigned short h) {
    return __uint_as_float(((unsigned int)h) << 16);
}

// ---------------- CSR build ----------------

__global__ void zero2_kernel(int* a, int* b, int n) {
    int i = blockIdx.x * 256 + threadIdx.x;
    if (i < n) { a[i] = 0; b[i] = 0; }
}

__global__ void hist_kernel(const int* __restrict__ ei, int* __restrict__ deg) {
    int e = blockIdx.x * 256 + threadIdx.x;
    if (e >= E_TOT) return;
    int d = (e < E_RAW) ? ei[E_RAW + e] : (e - E_RAW);
    atomicAdd(&deg[d], 1);
}

__global__ __launch_bounds__(1024) void scan_kernel(const int* __restrict__ deg,
                                                    int* __restrict__ offs) {
    __shared__ int part[1024];
    int t = threadIdx.x;
    const int chunk = (N_NODES + 1023) / 1024;  // 20
    int begin = t * chunk;
    int end = begin + chunk; if (end > N_NODES) end = N_NODES;
    if (begin > N_NODES) begin = N_NODES;
    int s = 0;
    for (int i = begin; i < end; i++) s += deg[i];
    part[t] = s;
    __syncthreads();
    for (int off = 1; off < 1024; off <<= 1) {
        int v = (t >= off) ? part[t - off] : 0;
        __syncthreads();
        part[t] += v;
        __syncthreads();
    }
    int run = (t == 0) ? 0 : part[t - 1];
    for (int i = begin; i < end; i++) { offs[i] = run; run += deg[i]; }
    if (t == 1023) offs[N_NODES] = part[1023];
}

__global__ void scatter_kernel(const int* __restrict__ ei, const int* __restrict__ offs,
                               int* __restrict__ cursor, int* __restrict__ csr) {
    int e = blockIdx.x * 256 + threadIdx.x;
    if (e >= E_TOT) return;
    int s, d;
    if (e < E_RAW) { s = ei[e]; d = ei[E_RAW + e]; }
    else           { s = e - E_RAW; d = s; }
    int pos = atomicAdd(&cursor[d], 1);
    csr[offs[d] + pos] = s;
}

// ---------------- W1 transpose+bf16 prepack: w1t[c][k] ----------------

__global__ void w1t_kernel(const float* __restrict__ W1, unsigned short* __restrict__ w1t) {
    int c = blockIdx.x;     // 256
    int k = threadIdx.x;    // 256
    w1t[c * IN_CH + k] = f2bf(W1[(size_t)k * HH + c]);
}

// ---------------- Layer 1 GEMM: MFMA bf16, 64 nodes x 256 cols, fused alpha ----
// 4 waves; wave w rows [16w,16w+16); 16 col-frags of 16. A staged in LDS (padded),
// B-frags loaded directly from prepacked w1t (L2-resident 128KB).
// mfma_f32_16x16x32_bf16: A[m=ln][k=q*8+j]; B[n=ln][k=q*8+j]; C/D col=ln,row=q*4+r.
#define G1_LDK 72
__global__ __launch_bounds__(256) void gemm1(const float* __restrict__ x,
                                             const unsigned short* __restrict__ w1t,
                                             const float* __restrict__ a1s,
                                             const float* __restrict__ a1d,
                                             unsigned short* __restrict__ h1b,
                                             float* __restrict__ as1,
                                             float* __restrict__ ad1) {
    __shared__ unsigned short As[64 * G1_LDK];   // 9 KiB
    int t = threadIdx.x;
    int wave = t >> 6, lane = t & 63;
    int ln = lane & 15, q = lane >> 4;
    int n0 = blockIdx.x * 64;

    floatx4 acc[16];
    #pragma unroll
    for (int f = 0; f < 16; f++) acc[f] = (floatx4){0.f, 0.f, 0.f, 0.f};

    int srow = t >> 4, scol = t & 15;
    const unsigned short* bl = w1t + (size_t)ln * IN_CH + q * 8;

    for (int kc = 0; kc < IN_CH; kc += 64) {
        #pragma unroll
        for (int pp = 0; pp < 4; pp++) {
            int row = srow + pp * 16;
            int n = n0 + row;
            float4 v = (n < N_NODES)
                ? *reinterpret_cast<const float4*>(&x[(size_t)n * IN_CH + kc + scol * 4])
                : make_float4(0.f, 0.f, 0.f, 0.f);
            ushort4 pv;
            pv.x = f2bf(v.x); pv.y = f2bf(v.y); pv.z = f2bf(v.z); pv.w = f2bf(v.w);
            *reinterpret_cast<ushort4*>(&As[row * G1_LDK + scol * 4]) = pv;
        }
        __syncthreads();
        #pragma unroll
        for (int ks = 0; ks < 2; ks++) {
            short8 a = *reinterpret_cast<const short8*>(
                &As[(16 * wave + ln) * G1_LDK + ks * 32 + q * 8]);
            #pragma unroll
            for (int f = 0; f < 16; f++) {
                short8 b = *reinterpret_cast<const short8*>(
                    bl + (size_t)f * 16 * IN_CH + kc + ks * 32);
                acc[f] = __builtin_amdgcn_mfma_f32_16x16x32_bf16(a, b, acc[f], 0, 0, 0);
            }
        }
        __syncthreads();
    }

    // epilogue: h1 store + fused per-head alpha dots from fp32 accs
    float Asr[16], Adr[16];
    #pragma unroll
    for (int f = 0; f < 16; f++) {
        Asr[f] = a1s[16 * f + ln];
        Adr[f] = a1d[16 * f + ln];
    }
    #pragma unroll
    for (int f = 0; f < 16; f++) {
        #pragma unroll
        for (int r = 0; r < 4; r++) {
            int n = n0 + 16 * wave + q * 4 + r;
            if (n < N_NODES)
                h1b[(size_t)n * HH + 16 * f + ln] = f2bf(acc[f][r]);
        }
    }
    #pragma unroll
    for (int h = 0; h < 8; h++) {
        #pragma unroll
        for (int r = 0; r < 4; r++) {
            float ps = acc[2*h][r] * Asr[2*h] + acc[2*h+1][r] * Asr[2*h+1];
            float pd = acc[2*h][r] * Adr[2*h] + acc[2*h+1][r] * Adr[2*h+1];
            ps += __shfl_xor(ps, 1); ps += __shfl_xor(ps, 2);
            ps += __shfl_xor(ps, 4); ps += __shfl_xor(ps, 8);
            pd += __shfl_xor(pd, 1); pd += __shfl_xor(pd, 2);
            pd += __shfl_xor(pd, 4); pd += __shfl_xor(pd, 8);
            int n = n0 + 16 * wave + q * 4 + r;
            if (ln == 0 && n < N_NODES) {
                as1[n * HEADS + h] = ps;
                ad1[n * HEADS + h] = pd;
            }
        }
    }
}

// ---------------- Layer 1 attention + aggregate + bias + ELU ----------------
// phase1: w = exp(leaky(as1[s]+ad1[d])) stored to wbuf (coalesced) + per-head sums.
// phase2: 16 edge-groups (wave*4+e4), lane = 16 channels, unnormalized accumulate;
// normalize by 1/denom in epilogue.

__global__ __launch_bounds__(256) void aggr1(const unsigned short* __restrict__ h1b,
                                             const float* __restrict__ as1,
                                             const float* __restrict__ ad1,
                                             const float* __restrict__ b1,
                                             const int* __restrict__ offs,
                                             const int* __restrict__ csr,
                                             float* __restrict__ wbuf,
                                             unsigned short* __restrict__ h2b) {
    int d = blockIdx.x;
    int t = threadIdx.x;
    int start = offs[d];
    int deg = offs[d + 1] - start;

    __shared__ float invh[8];
    __shared__ float psum[4][8];
    __shared__ float part2[16][HH];   // 16 KiB

    // ---- phase 1 ----
    {
        int j8 = t >> 3, h8 = t & 7;       // 32 edge slots x 8 heads
        float adv = ad1[d * HEADS + h8];
        float sum = 0.f;
        for (int base = 0; base < deg; base += 32) {
            int jj = base + j8;
            if (jj < deg) {
                int s = csr[start + jj];
                float v = as1[s * HEADS + h8] + adv;
                v = (v > 0.f) ? v : NEG * v;
                float w = __expf(v);
                wbuf[(size_t)(start + jj) * 8 + h8] = w;
                sum += w;
            }
        }
        sum += __shfl_xor(sum, 8);
        sum += __shfl_xor(sum, 16);
        sum += __shfl_xor(sum, 32);
        if ((t & 63) < 8) psum[t >> 6][t & 7] = sum;
    }
    __syncthreads();
    if (t < 8) invh[t] = 1.0f / (psum[0][t] + psum[1][t] + psum[2][t] + psum[3][t] + 1e-16f);
    __syncthreads();

    // ---- phase 2 ----
    int wave = t >> 6, lane = t & 63;
    int e4 = lane >> 4, cl = lane & 15;
    int cbase = cl * 16;          // 16 channels per lane
    int hh2 = cl >> 1;            // head of this channel group
    float acc[16];
    #pragma unroll
    for (int i = 0; i < 16; i++) acc[i] = 0.f;

    for (int jj = wave * 4 + e4; jj < deg; jj += 16) {
        int s = csr[start + jj];
        float w = wbuf[(size_t)(start + jj) * 8 + hh2];
        const unsigned short* hp = &h1b[(size_t)s * HH + cbase];
        short8 pa = *reinterpret_cast<const short8*>(hp);
        short8 pb = *reinterpret_cast<const short8*>(hp + 8);
        #pragma unroll
        for (int i = 0; i < 8; i++) {
            acc[i]     = fmaf(bf2f((unsigned short)pa[i]), w, acc[i]);
            acc[8 + i] = fmaf(bf2f((unsigned short)pb[i]), w, acc[8 + i]);
        }
    }
    int p = wave * 4 + e4;
    #pragma unroll
    for (int i = 0; i < 4; i++)
        *reinterpret_cast<float4*>(&part2[p][cbase + 4 * i]) =
            make_float4(acc[4*i], acc[4*i+1], acc[4*i+2], acc[4*i+3]);
    __syncthreads();

    float r = 0.f;
    #pragma unroll
    for (int pq = 0; pq < 16; pq++) r += part2[pq][t];
    r = r * invh[t >> 5] + b1[t];
    r = (r > 0.f) ? r : (__expf(r) - 1.f);   // ELU
    h2b[(size_t)d * HH + t] = f2bf(r);
}

// ---------------- Layer 2 GEMM + alpha ----------------

#define TM2 8
__global__ __launch_bounds__(320) void gemm2(const unsigned short* __restrict__ h2b,
                                             const float* __restrict__ W2,
                                             const float* __restrict__ a2s,
                                             const float* __restrict__ a2d,
                                             unsigned short* __restrict__ h3b,
                                             float* __restrict__ as2,
                                             float* __restrict__ ad2) {
    __shared__ float hs[TM2][HH];        // 8 KiB
    __shared__ float reds[TM2][OUT_CH];
    __shared__ float redd[TM2][OUT_CH];
    int t = threadIdx.x;
    int n0 = blockIdx.x * TM2;
    for (int i = t; i < TM2 * HH; i += 320)
        hs[i >> 8][i & 255] = bf2f(h2b[(size_t)n0 * HH + i]);
    __syncthreads();

    int m = t / OUT_CH;   // 0..7
    int c = t % OUT_CH;   // 0..39
    float acc = 0.f;
    for (int k = 0; k < HH; k += 4) {
        float4 hv = *reinterpret_cast<const float4*>(&hs[m][k]);
        acc = fmaf(hv.x, W2[(k + 0) * OUT_CH + c], acc);
        acc = fmaf(hv.y, W2[(k + 1) * OUT_CH + c], acc);
        acc = fmaf(hv.z, W2[(k + 2) * OUT_CH + c], acc);
        acc = fmaf(hv.w, W2[(k + 3) * OUT_CH + c], acc);
    }
    int n = n0 + m;
    h3b[(size_t)n * OUT_CH + c] = f2bf(acc);
    reds[m][c] = acc * a2s[c];
    redd[m][c] = acc * a2d[c];
    __syncthreads();
    if (t < TM2) {
        float ss = 0.f, sd = 0.f;
        for (int i = 0; i < OUT_CH; i++) { ss += reds[t][i]; sd += redd[t][i]; }
        as2[n0 + t] = ss;
        ad2[n0 + t] = sd;
    }
}

// ---------------- Layer 2 attention + aggregate + log_softmax ----------------
// wave per node (4/block); single pass: chunk weights in regs (shuffle-broadcast),
// unnormalized accumulate, divide by denom at the end. No max subtraction.

__global__ __launch_bounds__(256) void aggr2(const unsigned short* __restrict__ h3b,
                                             const float* __restrict__ as2,
                                             const float* __restrict__ ad2,
                                             const float* __restrict__ b2,
                                             const int* __restrict__ offs,
                                             const int* __restrict__ csr,
                                             float* __restrict__ out) {
    int d = blockIdx.x * 4 + (threadIdx.x >> 6);
    int lane = threadIdx.x & 63;
    int start = offs[d];
    int deg = offs[d + 1] - start;
    float adv = ad2[d];

    float a0 = 0.f, a1 = 0.f, a2 = 0.f, a3 = 0.f;
    float denom = 0.f;
    for (int base = 0; base < deg; base += 64) {
        int jj = base + lane;
        int s_reg = 0; float w_reg = 0.f;
        if (jj < deg) {
            s_reg = csr[start + jj];
            float v = as2[s_reg] + adv;
            v = (v > 0.f) ? v : NEG * v;
            w_reg = __expf(v);
        }
        float cs = w_reg;
        #pragma unroll
        for (int off = 32; off >= 1; off >>= 1) cs += __shfl_xor(cs, off);
        denom += cs;

        int lim = deg - base; if (lim > 64) lim = 64;
        int j2 = 0;
        for (; j2 + 3 < lim; j2 += 4) {
            int   s0 = __shfl(s_reg, j2 + 0), s1 = __shfl(s_reg, j2 + 1);
            int   s2 = __shfl(s_reg, j2 + 2), s3 = __shfl(s_reg, j2 + 3);
            float w0 = __shfl(w_reg, j2 + 0), w1 = __shfl(w_reg, j2 + 1);
            float w2 = __shfl(w_reg, j2 + 2), w3 = __shfl(w_reg, j2 + 3);
            if (lane < OUT_CH) {
                a0 = fmaf(bf2f(h3b[(size_t)s0 * OUT_CH + lane]), w0, a0);
                a1 = fmaf(bf2f(h3b[(size_t)s1 * OUT_CH + lane]), w1, a1);
                a2 = fmaf(bf2f(h3b[(size_t)s2 * OUT_CH + lane]), w2, a2);
                a3 = fmaf(bf2f(h3b[(size_t)s3 * OUT_CH + lane]), w3, a3);
            }
        }
        for (; j2 < lim; j2++) {
            int   s0 = __shfl(s_reg, j2);
            float w0 = __shfl(w_reg, j2);
            if (lane < OUT_CH)
                a0 = fmaf(bf2f(h3b[(size_t)s0 * OUT_CH + lane]), w0, a0);
        }
    }

    float r = (lane < OUT_CH)
        ? (a0 + a1 + a2 + a3) / (denom + 1e-16f) + b2[lane] : -1e30f;
    float mx = r;
    #pragma unroll
    for (int off = 32; off >= 1; off >>= 1) mx = fmaxf(mx, __shfl_xor(mx, off));
    float ex = (lane < OUT_CH) ? __expf(r - mx) : 0.f;
    float se = ex;
    #pragma unroll
    for (int off = 32; off >= 1; off >>= 1) se += __shfl_xor(se, off);
    if (lane < OUT_CH) out[(size_t)d * OUT_CH + lane] = r - mx - __logf(se);
}

// ---------------- host launcher ----------------

extern "C" void kernel_launch(void* const* d_in, const int* in_sizes, int n_in,
                              void* d_out, int out_size, void* d_ws, size_t ws_size,
                              hipStream_t stream) {
    const float* x   = (const float*)d_in[0];
    const int*   ei  = (const int*)  d_in[1];
    const float* W1  = (const float*)d_in[2];
    const float* a1s = (const float*)d_in[3];
    const float* a1d = (const float*)d_in[4];
    const float* b1  = (const float*)d_in[5];
    const float* W2  = (const float*)d_in[6];
    const float* a2s = (const float*)d_in[7];
    const float* a2d = (const float*)d_in[8];
    const float* b2  = (const float*)d_in[9];
    float* out = (float*)d_out;

    char* p = (char*)d_ws;
    auto alloc = [&](size_t bytes) {
        char* r = p;
        p += (bytes + 255) & ~(size_t)255;
        return r;
    };
    unsigned short* h1b = (unsigned short*)alloc((size_t)N_NODES * HH * 2);
    unsigned short* h2b = (unsigned short*)alloc((size_t)N_NODES * HH * 2);
    unsigned short* h3b = (unsigned short*)alloc((size_t)N_NODES * OUT_CH * 2);
    unsigned short* w1t = (unsigned short*)alloc((size_t)IN_CH * HH * 2);
    float* wbuf = (float*)alloc((size_t)E_TOT * HEADS * 4);
    float* as1  = (float*)alloc((size_t)N_NODES * HEADS * 4);
    float* ad1  = (float*)alloc((size_t)N_NODES * HEADS * 4);
    float* as2v = (float*)alloc((size_t)N_NODES * 4);
    float* ad2v = (float*)alloc((size_t)N_NODES * 4);
    int* deg    = (int*)alloc((size_t)N_NODES * 4);
    int* cursor = (int*)alloc((size_t)N_NODES * 4);
    int* offs   = (int*)alloc((size_t)(N_NODES + 1) * 4);
    int* csr    = (int*)alloc((size_t)E_TOT * 4);

    zero2_kernel<<<(N_NODES + 255) / 256, 256, 0, stream>>>(deg, cursor, N_NODES);
    hist_kernel<<<(E_TOT + 255) / 256, 256, 0, stream>>>(ei, deg);
    scan_kernel<<<1, 1024, 0, stream>>>(deg, offs);
    scatter_kernel<<<(E_TOT + 255) / 256, 256, 0, stream>>>(ei, offs, cursor, csr);

    w1t_kernel<<<HH, IN_CH, 0, stream>>>(W1, w1t);
    gemm1<<<(N_NODES + 63) / 64, 256, 0, stream>>>(x, w1t, a1s, a1d, h1b, as1, ad1);
    aggr1<<<N_NODES, 256, 0, stream>>>(h1b, as1, ad1, b1, offs, csr, wbuf, h2b);
    gemm2<<<N_NODES / TM2, 320, 0, stream>>>(h2b, W2, a2s, a2d, h3b, as2v, ad2v);
    aggr2<<<N_NODES / 4, 256, 0, stream>>>(h3b, as2v, ad2v, b2, offs, csr, out);
}

// Round 7
// 229.986 us; speedup vs baseline: 1.3671x; 1.2009x over previous
//
#include <hip/hip_runtime.h>
#include <math.h>

#define N_NODES 20000
#define E_RAW   320000
#define E_TOT   (E_RAW + N_NODES)
#define IN_CH   256
#define HEADS   8
#define HID     32
#define HH      (HEADS*HID)   // 256
#define OUT_CH  40
#define NC2     48            // OUT_CH padded to 3x16
#define NEG     0.2f

typedef __attribute__((ext_vector_type(8))) short  short8;
typedef __attribute__((ext_vector_type(4))) float  floatx4;

// bf16 helpers (bit-level, round-to-nearest-even; values are finite)
__device__ __forceinline__ unsigned short f2bf(float f) {
    unsigned int u = __float_as_uint(f);
    unsigned int r = (u + 0x7FFFu + ((u >> 16) & 1u)) >> 16;
    return (unsigned short)r;
}
__device__ __forceinline__ float bf2f(unsigned short h) {
    return __uint_as_float(((unsigned int)h) << 16);
}

// ---------------- CSR build ----------------

__global__ void zero2_kernel(int* a, int* b, int n) {
    int i = blockIdx.x * 256 + threadIdx.x;
    if (i < n) { a[i] = 0; b[i] = 0; }
}

__global__ void hist_kernel(const int* __restrict__ ei, int* __restrict__ deg) {
    int e = blockIdx.x * 256 + threadIdx.x;
    if (e >= E_TOT) return;
    int d = (e < E_RAW) ? ei[E_RAW + e] : (e - E_RAW);
    atomicAdd(&deg[d], 1);
}

__global__ __launch_bounds__(1024) void scan_kernel(const int* __restrict__ deg,
                                                    int* __restrict__ offs) {
    __shared__ int part[1024];
    int t = threadIdx.x;
    const int chunk = (N_NODES + 1023) / 1024;  // 20
    int begin = t * chunk;
    int end = begin + chunk; if (end > N_NODES) end = N_NODES;
    if (begin > N_NODES) begin = N_NODES;
    int s = 0;
    for (int i = begin; i < end; i++) s += deg[i];
    part[t] = s;
    __syncthreads();
    for (int off = 1; off < 1024; off <<= 1) {
        int v = (t >= off) ? part[t - off] : 0;
        __syncthreads();
        part[t] += v;
        __syncthreads();
    }
    int run = (t == 0) ? 0 : part[t - 1];
    for (int i = begin; i < end; i++) { offs[i] = run; run += deg[i]; }
    if (t == 1023) offs[N_NODES] = part[1023];
}

__global__ void scatter_kernel(const int* __restrict__ ei, const int* __restrict__ offs,
                               int* __restrict__ cursor, int* __restrict__ csr) {
    int e = blockIdx.x * 256 + threadIdx.x;
    if (e >= E_TOT) return;
    int s, d;
    if (e < E_RAW) { s = ei[e]; d = ei[E_RAW + e]; }
    else           { s = e - E_RAW; d = s; }
    int pos = atomicAdd(&cursor[d], 1);
    csr[offs[d] + pos] = s;
}

// ---------------- weight prepack: w1t[c][k] (256x256), w2t[c][k] (48x256) ----

__global__ void prepack_kernel(const float* __restrict__ W1,
                               const float* __restrict__ W2,
                               unsigned short* __restrict__ w1t,
                               unsigned short* __restrict__ w2t) {
    int k = threadIdx.x;    // 256
    int b = blockIdx.x;
    if (b < HH) {
        w1t[b * IN_CH + k] = f2bf(W1[(size_t)k * HH + b]);
    } else {
        int c = b - HH;     // 0..47
        w2t[c * HH + k] = (c < OUT_CH) ? f2bf(W2[(size_t)k * OUT_CH + c]) : 0;
    }
}

// ---------------- Layer 1 GEMM: MFMA bf16, 64x64 tile, fused alpha ----------
// grid = 313*4; block 256 = 4 waves. Wave w: rows [16w,16w+16), 4 col-frags.
// Each 64-col block spans exactly 2 heads -> alpha dots fully local.
// mfma_f32_16x16x32_bf16: A[m=ln][k=q*8+j]; B[n=ln][k=q*8+j]; C/D col=ln,row=q*4+r.
#define G1_LDK 72
__global__ __launch_bounds__(256) void gemm1(const float* __restrict__ x,
                                             const unsigned short* __restrict__ w1t,
                                             const float* __restrict__ a1s,
                                             const float* __restrict__ a1d,
                                             unsigned short* __restrict__ h1b,
                                             float* __restrict__ as1,
                                             float* __restrict__ ad1) {
    __shared__ unsigned short As[64 * G1_LDK];   // 9 KiB
    __shared__ unsigned short Bs[64 * G1_LDK];   // 9 KiB
    int t = threadIdx.x;
    int wave = t >> 6, lane = t & 63;
    int ln = lane & 15, q = lane >> 4;
    int bm = blockIdx.x >> 2;
    int bn = blockIdx.x & 3;
    int n0 = bm * 64;
    int c0 = bn * 64;

    floatx4 acc[4];
    #pragma unroll
    for (int f = 0; f < 4; f++) acc[f] = (floatx4){0.f, 0.f, 0.f, 0.f};

    int srow = t >> 4, scol = t & 15;

    for (int kc = 0; kc < IN_CH; kc += 64) {
        #pragma unroll
        for (int pp = 0; pp < 4; pp++) {
            int row = srow + pp * 16;
            int n = n0 + row;
            float4 v = (n < N_NODES)
                ? *reinterpret_cast<const float4*>(&x[(size_t)n * IN_CH + kc + scol * 4])
                : make_float4(0.f, 0.f, 0.f, 0.f);
            ushort4 pv;
            pv.x = f2bf(v.x); pv.y = f2bf(v.y); pv.z = f2bf(v.z); pv.w = f2bf(v.w);
            *reinterpret_cast<ushort4*>(&As[row * G1_LDK + scol * 4]) = pv;
            // B: direct bf16 copy from prepacked w1t
            *reinterpret_cast<ushort4*>(&Bs[row * G1_LDK + scol * 4]) =
                *reinterpret_cast<const ushort4*>(&w1t[(size_t)(c0 + row) * IN_CH + kc + scol * 4]);
        }
        __syncthreads();
        #pragma unroll
        for (int ks = 0; ks < 2; ks++) {
            short8 a = *reinterpret_cast<const short8*>(
                &As[(16 * wave + ln) * G1_LDK + ks * 32 + q * 8]);
            #pragma unroll
            for (int f = 0; f < 4; f++) {
                short8 b = *reinterpret_cast<const short8*>(
                    &Bs[(16 * f + ln) * G1_LDK + ks * 32 + q * 8]);
                acc[f] = __builtin_amdgcn_mfma_f32_16x16x32_bf16(a, b, acc[f], 0, 0, 0);
            }
        }
        __syncthreads();
    }

    // epilogue: h1 store + alpha dots for this block's 2 heads
    float Asr[4], Adr[4];
    #pragma unroll
    for (int f = 0; f < 4; f++) {
        Asr[f] = a1s[c0 + 16 * f + ln];
        Adr[f] = a1d[c0 + 16 * f + ln];
    }
    #pragma unroll
    for (int f = 0; f < 4; f++) {
        #pragma unroll
        for (int r = 0; r < 4; r++) {
            int n = n0 + 16 * wave + q * 4 + r;
            if (n < N_NODES)
                h1b[(size_t)n * HH + c0 + 16 * f + ln] = f2bf(acc[f][r]);
        }
    }
    int h0 = c0 >> 5;   // first head of this block
    #pragma unroll
    for (int lh = 0; lh < 2; lh++) {
        #pragma unroll
        for (int r = 0; r < 4; r++) {
            float ps = acc[2*lh][r] * Asr[2*lh] + acc[2*lh+1][r] * Asr[2*lh+1];
            float pd = acc[2*lh][r] * Adr[2*lh] + acc[2*lh+1][r] * Adr[2*lh+1];
            ps += __shfl_xor(ps, 1); ps += __shfl_xor(ps, 2);
            ps += __shfl_xor(ps, 4); ps += __shfl_xor(ps, 8);
            pd += __shfl_xor(pd, 1); pd += __shfl_xor(pd, 2);
            pd += __shfl_xor(pd, 4); pd += __shfl_xor(pd, 8);
            int n = n0 + 16 * wave + q * 4 + r;
            if (ln == 0 && n < N_NODES) {
                as1[n * HEADS + h0 + lh] = ps;
                ad1[n * HEADS + h0 + lh] = pd;
            }
        }
    }
}

// ---------------- Layer 1 attention + aggregate + bias + ELU ----------------
// phase1: w = exp(leaky(as1[s]+ad1[d])) stored to wbuf + per-head sums.
// phase2: 16 edge-groups, lane = 16 channels, unnormalized accumulate;
// normalize by 1/denom in epilogue.

__global__ __launch_bounds__(256) void aggr1(const unsigned short* __restrict__ h1b,
                                             const float* __restrict__ as1,
                                             const float* __restrict__ ad1,
                                             const float* __restrict__ b1,
                                             const int* __restrict__ offs,
                                             const int* __restrict__ csr,
                                             float* __restrict__ wbuf,
                                             unsigned short* __restrict__ h2b) {
    int d = blockIdx.x;
    int t = threadIdx.x;
    int start = offs[d];
    int deg = offs[d + 1] - start;

    __shared__ float invh[8];
    __shared__ float psum[4][8];
    __shared__ float part2[16][HH];   // 16 KiB

    // ---- phase 1 ----
    {
        int j8 = t >> 3, h8 = t & 7;       // 32 edge slots x 8 heads
        float adv = ad1[d * HEADS + h8];
        float sum = 0.f;
        for (int base = 0; base < deg; base += 32) {
            int jj = base + j8;
            if (jj < deg) {
                int s = csr[start + jj];
                float v = as1[s * HEADS + h8] + adv;
                v = (v > 0.f) ? v : NEG * v;
                float w = __expf(v);
                wbuf[(size_t)(start + jj) * 8 + h8] = w;
                sum += w;
            }
        }
        sum += __shfl_xor(sum, 8);
        sum += __shfl_xor(sum, 16);
        sum += __shfl_xor(sum, 32);
        if ((t & 63) < 8) psum[t >> 6][t & 7] = sum;
    }
    __syncthreads();
    if (t < 8) invh[t] = 1.0f / (psum[0][t] + psum[1][t] + psum[2][t] + psum[3][t] + 1e-16f);
    __syncthreads();

    // ---- phase 2 ----
    int wave = t >> 6, lane = t & 63;
    int e4 = lane >> 4, cl = lane & 15;
    int cbase = cl * 16;          // 16 channels per lane
    int hh2 = cl >> 1;            // head of this channel group
    float acc[16];
    #pragma unroll
    for (int i = 0; i < 16; i++) acc[i] = 0.f;

    for (int jj = wave * 4 + e4; jj < deg; jj += 16) {
        int s = csr[start + jj];
        float w = wbuf[(size_t)(start + jj) * 8 + hh2];
        const unsigned short* hp = &h1b[(size_t)s * HH + cbase];
        short8 pa = *reinterpret_cast<const short8*>(hp);
        short8 pb = *reinterpret_cast<const short8*>(hp + 8);
        #pragma unroll
        for (int i = 0; i < 8; i++) {
            acc[i]     = fmaf(bf2f((unsigned short)pa[i]), w, acc[i]);
            acc[8 + i] = fmaf(bf2f((unsigned short)pb[i]), w, acc[8 + i]);
        }
    }
    int p = wave * 4 + e4;
    #pragma unroll
    for (int i = 0; i < 4; i++)
        *reinterpret_cast<float4*>(&part2[p][cbase + 4 * i]) =
            make_float4(acc[4*i], acc[4*i+1], acc[4*i+2], acc[4*i+3]);
    __syncthreads();

    float r = 0.f;
    #pragma unroll
    for (int pq = 0; pq < 16; pq++) r += part2[pq][t];
    r = r * invh[t >> 5] + b1[t];
    r = (r > 0.f) ? r : (__expf(r) - 1.f);   // ELU
    h2b[(size_t)d * HH + t] = f2bf(r);
}

// ---------------- Layer 2 GEMM: MFMA bf16, 64 nodes x 48 cols, fused alpha ----
// grid 313; LDS: full-K A (64x256) + B (48x256), padded stride 264.
#define G2_LDK 264
__global__ __launch_bounds__(256) void gemm2(const unsigned short* __restrict__ h2b,
                                             const unsigned short* __restrict__ w2t,
                                             const float* __restrict__ a2s,
                                             const float* __restrict__ a2d,
                                             unsigned short* __restrict__ h3b,
                                             float* __restrict__ as2,
                                             float* __restrict__ ad2) {
    __shared__ unsigned short As2[64 * G2_LDK];  // 33 KiB
    __shared__ unsigned short Bs2[NC2 * G2_LDK]; // 24.8 KiB
    int t = threadIdx.x;
    int wave = t >> 6, lane = t & 63;
    int ln = lane & 15, q = lane >> 4;
    int n0 = blockIdx.x * 64;

    // stage A: 64 rows x 256 shorts; thread: row = t>>2, seg = t&3 (64 shorts = 8x short8)
    {
        int row = t >> 2, seg = t & 3;
        int n = n0 + row;
        #pragma unroll
        for (int i = 0; i < 8; i++) {
            short8 v;
            if (n < N_NODES)
                v = *reinterpret_cast<const short8*>(&h2b[(size_t)n * HH + seg * 64 + i * 8]);
            else
                v = (short8){0,0,0,0,0,0,0,0};
            *reinterpret_cast<short8*>(&As2[row * G2_LDK + seg * 64 + i * 8]) = v;
        }
    }
    // stage B: 48 rows x 256 shorts = 1536 short8 units
    for (int u = t; u < NC2 * 32; u += 256) {
        int row = u >> 5;
        int col = (u & 31) * 8;
        *reinterpret_cast<short8*>(&Bs2[row * G2_LDK + col]) =
            *reinterpret_cast<const short8*>(&w2t[(size_t)row * HH + col]);
    }
    __syncthreads();

    floatx4 acc[3];
    #pragma unroll
    for (int f = 0; f < 3; f++) acc[f] = (floatx4){0.f, 0.f, 0.f, 0.f};

    #pragma unroll
    for (int kf = 0; kf < 8; kf++) {
        short8 a = *reinterpret_cast<const short8*>(
            &As2[(16 * wave + ln) * G2_LDK + kf * 32 + q * 8]);
        #pragma unroll
        for (int f = 0; f < 3; f++) {
            short8 b = *reinterpret_cast<const short8*>(
                &Bs2[(16 * f + ln) * G2_LDK + kf * 32 + q * 8]);
            acc[f] = __builtin_amdgcn_mfma_f32_16x16x32_bf16(a, b, acc[f], 0, 0, 0);
        }
    }

    // epilogue: h3 store + alpha2 dots
    float a2sv[3], a2dv[3];
    #pragma unroll
    for (int f = 0; f < 3; f++) {
        int c = 16 * f + ln;
        a2sv[f] = (c < OUT_CH) ? a2s[c] : 0.f;
        a2dv[f] = (c < OUT_CH) ? a2d[c] : 0.f;
    }
    #pragma unroll
    for (int r = 0; r < 4; r++) {
        int n = n0 + 16 * wave + q * 4 + r;
        float ps = acc[0][r] * a2sv[0] + acc[1][r] * a2sv[1] + acc[2][r] * a2sv[2];
        float pd = acc[0][r] * a2dv[0] + acc[1][r] * a2dv[1] + acc[2][r] * a2dv[2];
        ps += __shfl_xor(ps, 1); ps += __shfl_xor(ps, 2);
        ps += __shfl_xor(ps, 4); ps += __shfl_xor(ps, 8);
        pd += __shfl_xor(pd, 1); pd += __shfl_xor(pd, 2);
        pd += __shfl_xor(pd, 4); pd += __shfl_xor(pd, 8);
        if (n < N_NODES) {
            #pragma unroll
            for (int f = 0; f < 3; f++) {
                int c = 16 * f + ln;
                if (c < OUT_CH)
                    h3b[(size_t)n * OUT_CH + c] = f2bf(acc[f][r]);
            }
            if (ln == 0) { as2[n] = ps; ad2[n] = pd; }
        }
    }
}

// ---------------- Layer 2 attention + aggregate + log_softmax ----------------

__global__ __launch_bounds__(256) void aggr2(const unsigned short* __restrict__ h3b,
                                             const float* __restrict__ as2,
                                             const float* __restrict__ ad2,
                                             const float* __restrict__ b2,
                                             const int* __restrict__ offs,
                                             const int* __restrict__ csr,
                                             float* __restrict__ out) {
    int d = blockIdx.x * 4 + (threadIdx.x >> 6);
    int lane = threadIdx.x & 63;
    int start = offs[d];
    int deg = offs[d + 1] - start;
    float adv = ad2[d];

    float a0 = 0.f, a1 = 0.f, a2 = 0.f, a3 = 0.f;
    float denom = 0.f;
    for (int base = 0; base < deg; base += 64) {
        int jj = base + lane;
        int s_reg = 0; float w_reg = 0.f;
        if (jj < deg) {
            s_reg = csr[start + jj];
            float v = as2[s_reg] + adv;
            v = (v > 0.f) ? v : NEG * v;
            w_reg = __expf(v);
        }
        float cs = w_reg;
        #pragma unroll
        for (int off = 32; off >= 1; off >>= 1) cs += __shfl_xor(cs, off);
        denom += cs;

        int lim = deg - base; if (lim > 64) lim = 64;
        int j2 = 0;
        for (; j2 + 3 < lim; j2 += 4) {
            int   s0 = __shfl(s_reg, j2 + 0), s1 = __shfl(s_reg, j2 + 1);
            int   s2 = __shfl(s_reg, j2 + 2), s3 = __shfl(s_reg, j2 + 3);
            float w0 = __shfl(w_reg, j2 + 0), w1 = __shfl(w_reg, j2 + 1);
            float w2 = __shfl(w_reg, j2 + 2), w3 = __shfl(w_reg, j2 + 3);
            if (lane < OUT_CH) {
                a0 = fmaf(bf2f(h3b[(size_t)s0 * OUT_CH + lane]), w0, a0);
                a1 = fmaf(bf2f(h3b[(size_t)s1 * OUT_CH + lane]), w1, a1);
                a2 = fmaf(bf2f(h3b[(size_t)s2 * OUT_CH + lane]), w2, a2);
                a3 = fmaf(bf2f(h3b[(size_t)s3 * OUT_CH + lane]), w3, a3);
            }
        }
        for (; j2 < lim; j2++) {
            int   s0 = __shfl(s_reg, j2);
            float w0 = __shfl(w_reg, j2);
            if (lane < OUT_CH)
                a0 = fmaf(bf2f(h3b[(size_t)s0 * OUT_CH + lane]), w0, a0);
        }
    }

    float r = (lane < OUT_CH)
        ? (a0 + a1 + a2 + a3) / (denom + 1e-16f) + b2[lane] : -1e30f;
    float mx = r;
    #pragma unroll
    for (int off = 32; off >= 1; off >>= 1) mx = fmaxf(mx, __shfl_xor(mx, off));
    float ex = (lane < OUT_CH) ? __expf(r - mx) : 0.f;
    float se = ex;
    #pragma unroll
    for (int off = 32; off >= 1; off >>= 1) se += __shfl_xor(se, off);
    if (lane < OUT_CH) out[(size_t)d * OUT_CH + lane] = r - mx - __logf(se);
}

// ---------------- host launcher ----------------

extern "C" void kernel_launch(void* const* d_in, const int* in_sizes, int n_in,
                              void* d_out, int out_size, void* d_ws, size_t ws_size,
                              hipStream_t stream) {
    const float* x   = (const float*)d_in[0];
    const int*   ei  = (const int*)  d_in[1];
    const float* W1  = (const float*)d_in[2];
    const float* a1s = (const float*)d_in[3];
    const float* a1d = (const float*)d_in[4];
    const float* b1  = (const float*)d_in[5];
    const float* W2  = (const float*)d_in[6];
    const float* a2s = (const float*)d_in[7];
    const float* a2d = (const float*)d_in[8];
    const float* b2  = (const float*)d_in[9];
    float* out = (float*)d_out;

    char* p = (char*)d_ws;
    auto alloc = [&](size_t bytes) {
        char* r = p;
        p += (bytes + 255) & ~(size_t)255;
        return r;
    };
    unsigned short* h1b = (unsigned short*)alloc((size_t)N_NODES * HH * 2);
    unsigned short* h2b = (unsigned short*)alloc((size_t)N_NODES * HH * 2);
    unsigned short* h3b = (unsigned short*)alloc((size_t)N_NODES * OUT_CH * 2);
    unsigned short* w1t = (unsigned short*)alloc((size_t)IN_CH * HH * 2);
    unsigned short* w2t = (unsigned short*)alloc((size_t)NC2 * HH * 2);
    float* wbuf = (float*)alloc((size_t)E_TOT * HEADS * 4);
    float* as1  = (float*)alloc((size_t)N_NODES * HEADS * 4);
    float* ad1  = (float*)alloc((size_t)N_NODES * HEADS * 4);
    float* as2v = (float*)alloc((size_t)N_NODES * 4);
    float* ad2v = (float*)alloc((size_t)N_NODES * 4);
    int* deg    = (int*)alloc((size_t)N_NODES * 4);
    int* cursor = (int*)alloc((size_t)N_NODES * 4);
    int* offs   = (int*)alloc((size_t)(N_NODES + 1) * 4);
    int* csr    = (int*)alloc((size_t)E_TOT * 4);

    zero2_kernel<<<(N_NODES + 255) / 256, 256, 0, stream>>>(deg, cursor, N_NODES);
    hist_kernel<<<(E_TOT + 255) / 256, 256, 0, stream>>>(ei, deg);
    scan_kernel<<<1, 1024, 0, stream>>>(deg, offs);
    scatter_kernel<<<(E_TOT + 255) / 256, 256, 0, stream>>>(ei, offs, cursor, csr);

    prepack_kernel<<<HH + NC2, IN_CH, 0, stream>>>(W1, W2, w1t, w2t);
    gemm1<<<313 * 4, 256, 0, stream>>>(x, w1t, a1s, a1d, h1b, as1, ad1);
    aggr1<<<N_NODES, 256, 0, stream>>>(h1b, as1, ad1, b1, offs, csr, wbuf, h2b);
    gemm2<<<313, 256, 0, stream>>>(h2b, w2t, a2s, a2d, h3b, as2v, ad2v);
    aggr2<<<N_NODES / 4, 256, 0, stream>>>(h3b, as2v, ad2v, b2, offs, csr, out);
}

// Round 8
// 223.797 us; speedup vs baseline: 1.4049x; 1.0277x over previous
//
#include <hip/hip_runtime.h>
#include <math.h>

#define N_NODES 20000
#define E_RAW   320000
#define E_TOT   (E_RAW + N_NODES)
#define IN_CH   256
#define HEADS   8
#define HID     32
#define HH      (HEADS*HID)   // 256
#define OUT_CH  40
#define NC2     48            // OUT_CH padded to 3x16
#define NEG     0.2f

typedef __attribute__((ext_vector_type(8))) short  short8;
typedef __attribute__((ext_vector_type(4))) float  floatx4;

// bf16 helpers (bit-level, round-to-nearest-even; values are finite)
__device__ __forceinline__ unsigned short f2bf(float f) {
    unsigned int u = __float_as_uint(f);
    unsigned int r = (u + 0x7FFFu + ((u >> 16) & 1u)) >> 16;
    return (unsigned short)r;
}
__device__ __forceinline__ float bf2f(unsigned short h) {
    return __uint_as_float(((unsigned int)h) << 16);
}

// ---------------- CSR build ----------------

__global__ void zero2_kernel(int* a, int n) {
    int i = blockIdx.x * 256 + threadIdx.x;
    if (i < n) a[i] = 0;
}

// histogram + record each edge's position within its dst bucket
__global__ void hist_kernel(const int* __restrict__ ei, int* __restrict__ deg,
                            int* __restrict__ pos) {
    int e = blockIdx.x * 256 + threadIdx.x;
    if (e >= E_TOT) return;
    int d = (e < E_RAW) ? ei[E_RAW + e] : (e - E_RAW);
    pos[e] = atomicAdd(&deg[d], 1);
}

__global__ __launch_bounds__(1024) void scan_kernel(const int* __restrict__ deg,
                                                    int* __restrict__ offs) {
    __shared__ int part[1024];
    int t = threadIdx.x;
    const int chunk = (N_NODES + 1023) / 1024;  // 20
    int begin = t * chunk;
    int end = begin + chunk; if (end > N_NODES) end = N_NODES;
    if (begin > N_NODES) begin = N_NODES;
    int s = 0;
    for (int i = begin; i < end; i++) s += deg[i];
    part[t] = s;
    __syncthreads();
    for (int off = 1; off < 1024; off <<= 1) {
        int v = (t >= off) ? part[t - off] : 0;
        __syncthreads();
        part[t] += v;
        __syncthreads();
    }
    int run = (t == 0) ? 0 : part[t - 1];
    for (int i = begin; i < end; i++) { offs[i] = run; run += deg[i]; }
    if (t == 1023) offs[N_NODES] = part[1023];
}

__global__ void scatter_kernel(const int* __restrict__ ei, const int* __restrict__ offs,
                               const int* __restrict__ pos, int* __restrict__ csr) {
    int e = blockIdx.x * 256 + threadIdx.x;
    if (e >= E_TOT) return;
    int s, d;
    if (e < E_RAW) { s = ei[e]; d = ei[E_RAW + e]; }
    else           { s = e - E_RAW; d = s; }
    csr[offs[d] + pos[e]] = s;
}

// ---------------- weight prepack: w1t[c][k] (256x256), w2t[c][k] (48x256) ----

__global__ void prepack_kernel(const float* __restrict__ W1,
                               const float* __restrict__ W2,
                               unsigned short* __restrict__ w1t,
                               unsigned short* __restrict__ w2t) {
    int k = threadIdx.x;    // 256
    int b = blockIdx.x;
    if (b < HH) {
        w1t[b * IN_CH + k] = f2bf(W1[(size_t)k * HH + b]);
    } else {
        int c = b - HH;     // 0..47
        w2t[c * HH + k] = (c < OUT_CH) ? f2bf(W2[(size_t)k * OUT_CH + c]) : 0;
    }
}

// ---------------- Layer 1 GEMM: MFMA bf16, 64x64 tile, fused alpha ----------
// grid = 313*4; block 256 = 4 waves. Wave w: rows [16w,16w+16), 4 col-frags.
// Each 64-col block spans exactly 2 heads -> alpha dots fully local.
// mfma_f32_16x16x32_bf16: A[m=ln][k=q*8+j]; B[n=ln][k=q*8+j]; C/D col=ln,row=q*4+r.
#define G1_LDK 72
__global__ __launch_bounds__(256) void gemm1(const float* __restrict__ x,
                                             const unsigned short* __restrict__ w1t,
                                             const float* __restrict__ a1s,
                                             const float* __restrict__ a1d,
                                             unsigned short* __restrict__ h1b,
                                             float* __restrict__ as1,
                                             float* __restrict__ ad1) {
    __shared__ unsigned short As[64 * G1_LDK];   // 9 KiB
    __shared__ unsigned short Bs[64 * G1_LDK];   // 9 KiB
    int t = threadIdx.x;
    int wave = t >> 6, lane = t & 63;
    int ln = lane & 15, q = lane >> 4;
    int bm = blockIdx.x >> 2;
    int bn = blockIdx.x & 3;
    int n0 = bm * 64;
    int c0 = bn * 64;

    floatx4 acc[4];
    #pragma unroll
    for (int f = 0; f < 4; f++) acc[f] = (floatx4){0.f, 0.f, 0.f, 0.f};

    int srow = t >> 4, scol = t & 15;

    for (int kc = 0; kc < IN_CH; kc += 64) {
        #pragma unroll
        for (int pp = 0; pp < 4; pp++) {
            int row = srow + pp * 16;
            int n = n0 + row;
            float4 v = (n < N_NODES)
                ? *reinterpret_cast<const float4*>(&x[(size_t)n * IN_CH + kc + scol * 4])
                : make_float4(0.f, 0.f, 0.f, 0.f);
            ushort4 pv;
            pv.x = f2bf(v.x); pv.y = f2bf(v.y); pv.z = f2bf(v.z); pv.w = f2bf(v.w);
            *reinterpret_cast<ushort4*>(&As[row * G1_LDK + scol * 4]) = pv;
            // B: direct bf16 copy from prepacked w1t
            *reinterpret_cast<ushort4*>(&Bs[row * G1_LDK + scol * 4]) =
                *reinterpret_cast<const ushort4*>(&w1t[(size_t)(c0 + row) * IN_CH + kc + scol * 4]);
        }
        __syncthreads();
        #pragma unroll
        for (int ks = 0; ks < 2; ks++) {
            short8 a = *reinterpret_cast<const short8*>(
                &As[(16 * wave + ln) * G1_LDK + ks * 32 + q * 8]);
            #pragma unroll
            for (int f = 0; f < 4; f++) {
                short8 b = *reinterpret_cast<const short8*>(
                    &Bs[(16 * f + ln) * G1_LDK + ks * 32 + q * 8]);
                acc[f] = __builtin_amdgcn_mfma_f32_16x16x32_bf16(a, b, acc[f], 0, 0, 0);
            }
        }
        __syncthreads();
    }

    // epilogue: h1 store + alpha dots for this block's 2 heads
    float Asr[4], Adr[4];
    #pragma unroll
    for (int f = 0; f < 4; f++) {
        Asr[f] = a1s[c0 + 16 * f + ln];
        Adr[f] = a1d[c0 + 16 * f + ln];
    }
    #pragma unroll
    for (int f = 0; f < 4; f++) {
        #pragma unroll
        for (int r = 0; r < 4; r++) {
            int n = n0 + 16 * wave + q * 4 + r;
            if (n < N_NODES)
                h1b[(size_t)n * HH + c0 + 16 * f + ln] = f2bf(acc[f][r]);
        }
    }
    int h0 = c0 >> 5;   // first head of this block
    #pragma unroll
    for (int lh = 0; lh < 2; lh++) {
        #pragma unroll
        for (int r = 0; r < 4; r++) {
            float ps = acc[2*lh][r] * Asr[2*lh] + acc[2*lh+1][r] * Asr[2*lh+1];
            float pd = acc[2*lh][r] * Adr[2*lh] + acc[2*lh+1][r] * Adr[2*lh+1];
            ps += __shfl_xor(ps, 1); ps += __shfl_xor(ps, 2);
            ps += __shfl_xor(ps, 4); ps += __shfl_xor(ps, 8);
            pd += __shfl_xor(pd, 1); pd += __shfl_xor(pd, 2);
            pd += __shfl_xor(pd, 4); pd += __shfl_xor(pd, 8);
            int n = n0 + 16 * wave + q * 4 + r;
            if (ln == 0 && n < N_NODES) {
                as1[n * HEADS + h0 + lh] = ps;
                ad1[n * HEADS + h0 + lh] = pd;
            }
        }
    }
}

// ---------------- Layer 1 attention + aggregate + bias + ELU ----------------
// phase1: w = exp(leaky(as1[s]+ad1[d])) stored to wbuf + per-head sums.
// phase2: 16 edge-slots (wave,e4), lane = 16 channels; slot partials combined
// by in-wave shfl_xor(16/32), then one conflict-free float4 per lane into
// part2[4][HH]; normalize by 1/denom in epilogue.

__global__ __launch_bounds__(256) void aggr1(const unsigned short* __restrict__ h1b,
                                             const float* __restrict__ as1,
                                             const float* __restrict__ ad1,
                                             const float* __restrict__ b1,
                                             const int* __restrict__ offs,
                                             const int* __restrict__ csr,
                                             float* __restrict__ wbuf,
                                             unsigned short* __restrict__ h2b) {
    int d = blockIdx.x;
    int t = threadIdx.x;
    int start = offs[d];
    int deg = offs[d + 1] - start;

    __shared__ float invh[8];
    __shared__ float psum[4][8];
    __shared__ float part2[4][HH];    // 4 KiB

    // ---- phase 1 ----
    {
        int j8 = t >> 3, h8 = t & 7;       // 32 edge slots x 8 heads
        float adv = ad1[d * HEADS + h8];
        float sum = 0.f;
        for (int base = 0; base < deg; base += 32) {
            int jj = base + j8;
            if (jj < deg) {
                int s = csr[start + jj];
                float v = as1[s * HEADS + h8] + adv;
                v = (v > 0.f) ? v : NEG * v;
                float w = __expf(v);
                wbuf[(size_t)(start + jj) * 8 + h8] = w;
                sum += w;
            }
        }
        sum += __shfl_xor(sum, 8);
        sum += __shfl_xor(sum, 16);
        sum += __shfl_xor(sum, 32);
        if ((t & 63) < 8) psum[t >> 6][t & 7] = sum;
    }
    __syncthreads();
    if (t < 8) invh[t] = 1.0f / (psum[0][t] + psum[1][t] + psum[2][t] + psum[3][t] + 1e-16f);
    __syncthreads();

    // ---- phase 2 ----
    int wave = t >> 6, lane = t & 63;
    int e4 = lane >> 4, cl = lane & 15;
    int cbase = cl * 16;          // 16 channels per lane
    int hh2 = cl >> 1;            // head of this channel group
    float acc[16];
    #pragma unroll
    for (int i = 0; i < 16; i++) acc[i] = 0.f;

    for (int jj = wave * 4 + e4; jj < deg; jj += 16) {
        int s = csr[start + jj];
        float w = wbuf[(size_t)(start + jj) * 8 + hh2];
        const unsigned short* hp = &h1b[(size_t)s * HH + cbase];
        short8 pa = *reinterpret_cast<const short8*>(hp);
        short8 pb = *reinterpret_cast<const short8*>(hp + 8);
        #pragma unroll
        for (int i = 0; i < 8; i++) {
            acc[i]     = fmaf(bf2f((unsigned short)pa[i]), w, acc[i]);
            acc[8 + i] = fmaf(bf2f((unsigned short)pb[i]), w, acc[8 + i]);
        }
    }
    // in-wave reduction across the 4 edge-slots (e4 quarters)
    #pragma unroll
    for (int i = 0; i < 16; i++) {
        acc[i] += __shfl_xor(acc[i], 16);
        acc[i] += __shfl_xor(acc[i], 32);
    }
    // each quarter writes its quarter of the channel block: bank-uniform
    float4 outv = (e4 == 0) ? make_float4(acc[0],  acc[1],  acc[2],  acc[3])
                : (e4 == 1) ? make_float4(acc[4],  acc[5],  acc[6],  acc[7])
                : (e4 == 2) ? make_float4(acc[8],  acc[9],  acc[10], acc[11])
                :             make_float4(acc[12], acc[13], acc[14], acc[15]);
    *reinterpret_cast<float4*>(&part2[wave][cbase + e4 * 4]) = outv;
    __syncthreads();

    float r = part2[0][t] + part2[1][t] + part2[2][t] + part2[3][t];
    r = r * invh[t >> 5] + b1[t];
    r = (r > 0.f) ? r : (__expf(r) - 1.f);   // ELU
    h2b[(size_t)d * HH + t] = f2bf(r);
}

// ---------------- Layer 2 GEMM: MFMA bf16, 64 nodes x 48 cols, fused alpha ----
// grid 313; LDS: full-K A (64x256) + B (48x256), padded stride 264.
#define G2_LDK 264
__global__ __launch_bounds__(256) void gemm2(const unsigned short* __restrict__ h2b,
                                             const unsigned short* __restrict__ w2t,
                                             const float* __restrict__ a2s,
                                             const float* __restrict__ a2d,
                                             unsigned short* __restrict__ h3b,
                                             float* __restrict__ as2,
                                             float* __restrict__ ad2) {
    __shared__ unsigned short As2[64 * G2_LDK];  // 33 KiB
    __shared__ unsigned short Bs2[NC2 * G2_LDK]; // 24.8 KiB
    int t = threadIdx.x;
    int wave = t >> 6, lane = t & 63;
    int ln = lane & 15, q = lane >> 4;
    int n0 = blockIdx.x * 64;

    // stage A: 64 rows x 256 shorts; thread: row = t>>2, seg = t&3 (64 shorts = 8x short8)
    {
        int row = t >> 2, seg = t & 3;
        int n = n0 + row;
        #pragma unroll
        for (int i = 0; i < 8; i++) {
            short8 v;
            if (n < N_NODES)
                v = *reinterpret_cast<const short8*>(&h2b[(size_t)n * HH + seg * 64 + i * 8]);
            else
                v = (short8){0,0,0,0,0,0,0,0};
            *reinterpret_cast<short8*>(&As2[row * G2_LDK + seg * 64 + i * 8]) = v;
        }
    }
    // stage B: 48 rows x 256 shorts = 1536 short8 units
    for (int u = t; u < NC2 * 32; u += 256) {
        int row = u >> 5;
        int col = (u & 31) * 8;
        *reinterpret_cast<short8*>(&Bs2[row * G2_LDK + col]) =
            *reinterpret_cast<const short8*>(&w2t[(size_t)row * HH + col]);
    }
    __syncthreads();

    floatx4 acc[3];
    #pragma unroll
    for (int f = 0; f < 3; f++) acc[f] = (floatx4){0.f, 0.f, 0.f, 0.f};

    #pragma unroll
    for (int kf = 0; kf < 8; kf++) {
        short8 a = *reinterpret_cast<const short8*>(
            &As2[(16 * wave + ln) * G2_LDK + kf * 32 + q * 8]);
        #pragma unroll
        for (int f = 0; f < 3; f++) {
            short8 b = *reinterpret_cast<const short8*>(
                &Bs2[(16 * f + ln) * G2_LDK + kf * 32 + q * 8]);
            acc[f] = __builtin_amdgcn_mfma_f32_16x16x32_bf16(a, b, acc[f], 0, 0, 0);
        }
    }

    // epilogue: h3 store + alpha2 dots
    float a2sv[3], a2dv[3];
    #pragma unroll
    for (int f = 0; f < 3; f++) {
        int c = 16 * f + ln;
        a2sv[f] = (c < OUT_CH) ? a2s[c] : 0.f;
        a2dv[f] = (c < OUT_CH) ? a2d[c] : 0.f;
    }
    #pragma unroll
    for (int r = 0; r < 4; r++) {
        int n = n0 + 16 * wave + q * 4 + r;
        float ps = acc[0][r] * a2sv[0] + acc[1][r] * a2sv[1] + acc[2][r] * a2sv[2];
        float pd = acc[0][r] * a2dv[0] + acc[1][r] * a2dv[1] + acc[2][r] * a2dv[2];
        ps += __shfl_xor(ps, 1); ps += __shfl_xor(ps, 2);
        ps += __shfl_xor(ps, 4); ps += __shfl_xor(ps, 8);
        pd += __shfl_xor(pd, 1); pd += __shfl_xor(pd, 2);
        pd += __shfl_xor(pd, 4); pd += __shfl_xor(pd, 8);
        if (n < N_NODES) {
            #pragma unroll
            for (int f = 0; f < 3; f++) {
                int c = 16 * f + ln;
                if (c < OUT_CH)
                    h3b[(size_t)n * OUT_CH + c] = f2bf(acc[f][r]);
            }
            if (ln == 0) { as2[n] = ps; ad2[n] = pd; }
        }
    }
}

// ---------------- Layer 2 attention + aggregate + log_softmax ----------------

__global__ __launch_bounds__(256) void aggr2(const unsigned short* __restrict__ h3b,
                                             const float* __restrict__ as2,
                                             const float* __restrict__ ad2,
                                             const float* __restrict__ b2,
                                             const int* __restrict__ offs,
                                             const int* __restrict__ csr,
                                             float* __restrict__ out) {
    int d = blockIdx.x * 4 + (threadIdx.x >> 6);
    int lane = threadIdx.x & 63;
    int start = offs[d];
    int deg = offs[d + 1] - start;
    float adv = ad2[d];

    float a0 = 0.f, a1 = 0.f, a2 = 0.f, a3 = 0.f;
    float denom = 0.f;
    for (int base = 0; base < deg; base += 64) {
        int jj = base + lane;
        int s_reg = 0; float w_reg = 0.f;
        if (jj < deg) {
            s_reg = csr[start + jj];
            float v = as2[s_reg] + adv;
            v = (v > 0.f) ? v : NEG * v;
            w_reg = __expf(v);
        }
        float cs = w_reg;
        #pragma unroll
        for (int off = 32; off >= 1; off >>= 1) cs += __shfl_xor(cs, off);
        denom += cs;

        int lim = deg - base; if (lim > 64) lim = 64;
        int j2 = 0;
        for (; j2 + 3 < lim; j2 += 4) {
            int   s0 = __shfl(s_reg, j2 + 0), s1 = __shfl(s_reg, j2 + 1);
            int   s2 = __shfl(s_reg, j2 + 2), s3 = __shfl(s_reg, j2 + 3);
            float w0 = __shfl(w_reg, j2 + 0), w1 = __shfl(w_reg, j2 + 1);
            float w2 = __shfl(w_reg, j2 + 2), w3 = __shfl(w_reg, j2 + 3);
            if (lane < OUT_CH) {
                a0 = fmaf(bf2f(h3b[(size_t)s0 * OUT_CH + lane]), w0, a0);
                a1 = fmaf(bf2f(h3b[(size_t)s1 * OUT_CH + lane]), w1, a1);
                a2 = fmaf(bf2f(h3b[(size_t)s2 * OUT_CH + lane]), w2, a2);
                a3 = fmaf(bf2f(h3b[(size_t)s3 * OUT_CH + lane]), w3, a3);
            }
        }
        for (; j2 < lim; j2++) {
            int   s0 = __shfl(s_reg, j2);
            float w0 = __shfl(w_reg, j2);
            if (lane < OUT_CH)
                a0 = fmaf(bf2f(h3b[(size_t)s0 * OUT_CH + lane]), w0, a0);
        }
    }

    float r = (lane < OUT_CH)
        ? (a0 + a1 + a2 + a3) / (denom + 1e-16f) + b2[lane] : -1e30f;
    float mx = r;
    #pragma unroll
    for (int off = 32; off >= 1; off >>= 1) mx = fmaxf(mx, __shfl_xor(mx, off));
    float ex = (lane < OUT_CH) ? __expf(r - mx) : 0.f;
    float se = ex;
    #pragma unroll
    for (int off = 32; off >= 1; off >>= 1) se += __shfl_xor(se, off);
    if (lane < OUT_CH) out[(size_t)d * OUT_CH + lane] = r - mx - __logf(se);
}

// ---------------- host launcher ----------------

extern "C" void kernel_launch(void* const* d_in, const int* in_sizes, int n_in,
                              void* d_out, int out_size, void* d_ws, size_t ws_size,
                              hipStream_t stream) {
    const float* x   = (const float*)d_in[0];
    const int*   ei  = (const int*)  d_in[1];
    const float* W1  = (const float*)d_in[2];
    const float* a1s = (const float*)d_in[3];
    const float* a1d = (const float*)d_in[4];
    const float* b1  = (const float*)d_in[5];
    const float* W2  = (const float*)d_in[6];
    const float* a2s = (const float*)d_in[7];
    const float* a2d = (const float*)d_in[8];
    const float* b2  = (const float*)d_in[9];
    float* out = (float*)d_out;

    char* p = (char*)d_ws;
    auto alloc = [&](size_t bytes) {
        char* r = p;
        p += (bytes + 255) & ~(size_t)255;
        return r;
    };
    unsigned short* h1b = (unsigned short*)alloc((size_t)N_NODES * HH * 2);
    unsigned short* h2b = (unsigned short*)alloc((size_t)N_NODES * HH * 2);
    unsigned short* h3b = (unsigned short*)alloc((size_t)N_NODES * OUT_CH * 2);
    unsigned short* w1t = (unsigned short*)alloc((size_t)IN_CH * HH * 2);
    unsigned short* w2t = (unsigned short*)alloc((size_t)NC2 * HH * 2);
    float* wbuf = (float*)alloc((size_t)E_TOT * HEADS * 4);
    float* as1  = (float*)alloc((size_t)N_NODES * HEADS * 4);
    float* ad1  = (float*)alloc((size_t)N_NODES * HEADS * 4);
    float* as2v = (float*)alloc((size_t)N_NODES * 4);
    float* ad2v = (float*)alloc((size_t)N_NODES * 4);
    int* deg    = (int*)alloc((size_t)N_NODES * 4);
    int* pos    = (int*)alloc((size_t)E_TOT * 4);
    int* offs   = (int*)alloc((size_t)(N_NODES + 1) * 4);
    int* csr    = (int*)alloc((size_t)E_TOT * 4);

    zero2_kernel<<<(N_NODES + 255) / 256, 256, 0, stream>>>(deg, N_NODES);
    hist_kernel<<<(E_TOT + 255) / 256, 256, 0, stream>>>(ei, deg, pos);
    scan_kernel<<<1, 1024, 0, stream>>>(deg, offs);
    scatter_kernel<<<(E_TOT + 255) / 256, 256, 0, stream>>>(ei, offs, pos, csr);

    prepack_kernel<<<HH + NC2, IN_CH, 0, stream>>>(W1, W2, w1t, w2t);
    gemm1<<<313 * 4, 256, 0, stream>>>(x, w1t, a1s, a1d, h1b, as1, ad1);
    aggr1<<<N_NODES, 256, 0, stream>>>(h1b, as1, ad1, b1, offs, csr, wbuf, h2b);
    gemm2<<<313, 256, 0, stream>>>(h2b, w2t, a2s, a2d, h3b, as2v, ad2v);
    aggr2<<<N_NODES / 4, 256, 0, stream>>>(h3b, as2v, ad2v, b2, offs, csr, out);
}